// Round 10
// baseline (363.674 us; speedup 1.0000x reference)
//
#include <hip/hip_runtime.h>
#include <cstdint>
#include <cstddef>

#define NB 2
#define NL 2048
#define ND 1024
#define NH 16
#define NDH 64
#define NDFF 4096

typedef __bf16 bf16_t;
typedef bf16_t bf16x8 __attribute__((ext_vector_type(8)));
typedef float f32x4 __attribute__((ext_vector_type(4)));

__device__ __forceinline__ float bf2f(unsigned short h) {
  union { unsigned u; float f; } c; c.u = ((unsigned)h) << 16; return c.f;
}
__device__ __forceinline__ unsigned short f2bf(float f) {
  union { float f; unsigned u; } c; c.f = f;
  return (unsigned short)((c.u + 0x7fffu + ((c.u >> 16) & 1u)) >> 16);
}

// async global->LDS, 16B per lane; lds base must be wave-uniform.
__device__ __forceinline__ void async_copy16(const void* g, void* l) {
  __builtin_amdgcn_global_load_lds(
      (const __attribute__((address_space(1))) void*)g,
      (__attribute__((address_space(3))) void*)l, 16, 0, 0);
}

// ---------------------------------------------------------------------------
// Fused f32 -> bf16 cast of x + all 4 weight matrices, one launch.
// ---------------------------------------------------------------------------
__global__ __launch_bounds__(256) void cast_all(
    const float* __restrict__ x, const float* __restrict__ wqkv,
    const float* __restrict__ wo, const float* __restrict__ w1,
    const float* __restrict__ w2, unsigned short* __restrict__ xb,
    unsigned short* __restrict__ wqkvb, unsigned short* __restrict__ wob,
    unsigned short* __restrict__ w1b, unsigned short* __restrict__ w2b) {
  const int i = blockIdx.x * 256 + threadIdx.x;
  const float* src;
  unsigned short* dst;
  int off;
  if (i < 1048576) { src = x; dst = xb; off = i; }  // 4M elems (vec4)
  else if (i < 1835008) { src = wqkv; dst = wqkvb; off = i - 1048576; }
  else if (i < 2097152) { src = wo; dst = wob; off = i - 1835008; }
  else if (i < 3145728) { src = w1; dst = w1b; off = i - 2097152; }
  else { src = w2; dst = w2b; off = i - 3145728; }
  const float4 v = ((const float4*)src)[off];
  ushort4 o;
  o.x = f2bf(v.x); o.y = f2bf(v.y); o.z = f2bf(v.z); o.w = f2bf(v.w);
  ((ushort4*)dst)[off] = o;
}

// ---------------------------------------------------------------------------
// 256x256 8-wave GEMM, BK=64 (T2+T3/T4+T5 port of the verified 8-phase
// template). C[M,N] = A[M,K]@W[N,K]^T + bias, bf16 out, optional ReLU.
// 512 threads = 8 waves (2M x 4N), per-wave C = 128x64 (8x4 16x16 frags).
// LDS 128 KiB: As/Bs[2][256*64] double-buffered -> 1 block/CU, 2 waves/SIMD.
// Schedule per K-tile: {stage next tile (8 global_load_lds); vmcnt(8)
// COUNTED (waits only loads issued one full K-tile ago); raw s_barrier
// (no implicit vmcnt(0) drain); 4 phases x {12 ds_read_b128, setprio(1),
// 16 MFMA, setprio(0)}; s_barrier}. Swizzle (rule #21, both-sides):
// linear LDS dest, global SOURCE granule pre-XOR'd by (row&7), ds_read
// address XOR'd the same -> each 8-lane phase of a b128 read hits 8
// distinct 4-bank spans (conflict-free).
// ---------------------------------------------------------------------------
template <bool RELU>
__global__ __launch_bounds__(512, 2) void gemm256(
    const unsigned short* __restrict__ A, const unsigned short* __restrict__ W,
    const float* __restrict__ bias, unsigned short* __restrict__ outb,
    int M, int N, int K) {
  const int tid = threadIdx.x;
  const int lane = tid & 63;
  const int wid = tid >> 6;
  const int wm = wid >> 2, wn = wid & 3;
  const int quad = lane >> 4, l16 = lane & 15;

  // XCD-aware remap (gy multiple of 8)
  const int gx = gridDim.x, gy = gridDim.y;
  int bx = blockIdx.x, by = blockIdx.y;
  if ((gy & 7) == 0) {
    const int i = blockIdx.x + gx * blockIdx.y;
    const int g = i & 7, s = i >> 3;
    const int yg = gy >> 3;
    by = g * yg + (s % yg);
    bx = (s / yg) % gx;
  }
  const int m0 = by * 256, n0 = bx * 256;

  __shared__ __align__(16) unsigned short As[2][256 * 64];
  __shared__ __align__(16) unsigned short Bs[2][256 * 64];

  // staging: load l covers row l*64 + (tid>>3); source granule pre-swizzled
  const int srow = tid >> 3;                 // 0..63
  const int gsrc = (tid & 7) ^ (srow & 7);   // logical granule for this slot
  const unsigned short* Ag = A + (size_t)(m0 + srow) * K + gsrc * 8;
  const unsigned short* Bg = W + (size_t)(n0 + srow) * K + gsrc * 8;
  const int ldst = srow * 64 + (tid & 7) * 8;  // linear LDS elem offset

  f32x4 acc[8][4];
#pragma unroll
  for (int i = 0; i < 8; i++)
#pragma unroll
    for (int j = 0; j < 4; j++) acc[i][j] = (f32x4){0.f, 0.f, 0.f, 0.f};

  auto stage = [&](int kt, int bsel) {
#pragma unroll
    for (int l = 0; l < 4; l++)
      async_copy16(Ag + (size_t)(l * 64) * K + kt * 64,
                   &As[bsel][l * 64 * 64 + ldst]);
#pragma unroll
    for (int l = 0; l < 4; l++)
      async_copy16(Bg + (size_t)(l * 64) * K + kt * 64,
                   &Bs[bsel][l * 64 * 64 + ldst]);
  };

  // read-side addressing: row&7 == l16&7 for both A and B fragments
  const int arow = wm * 128 + l16;  // + mf*16
  const int brow = wn * 64 + l16;   // + nf*16
  const int r7 = l16 & 7;

  const int NT = K >> 6;
  int b = 0;
  stage(0, 0);
  for (int kt = 0; kt < NT; kt++) {
    if (kt + 1 < NT) {
      stage(kt + 1, b ^ 1);  // 8 more loads in flight
      asm volatile("s_waitcnt vmcnt(8)" ::: "memory");  // this tile's done
    } else {
      asm volatile("s_waitcnt vmcnt(0)" ::: "memory");
    }
    __builtin_amdgcn_s_barrier();  // all waves' staging visible

#pragma unroll
    for (int ph = 0; ph < 4; ph++) {
      const int mh = ph >> 1, nh = ph & 1;
      bf16x8 a_[4][2], b_[2][2];
#pragma unroll
      for (int mf = 0; mf < 4; mf++)
#pragma unroll
        for (int kk = 0; kk < 2; kk++)
          a_[mf][kk] = *(const bf16x8*)&As[b][(arow + (mh * 4 + mf) * 16) * 64 +
                                             (((quad + kk * 4) ^ r7) * 8)];
#pragma unroll
      for (int nf = 0; nf < 2; nf++)
#pragma unroll
        for (int kk = 0; kk < 2; kk++)
          b_[nf][kk] = *(const bf16x8*)&Bs[b][(brow + (nh * 2 + nf) * 16) * 64 +
                                             (((quad + kk * 4) ^ r7) * 8)];
      __builtin_amdgcn_s_setprio(1);
#pragma unroll
      for (int mf = 0; mf < 4; mf++)
#pragma unroll
        for (int nf = 0; nf < 2; nf++)
#pragma unroll
          for (int kk = 0; kk < 2; kk++)
            acc[mh * 4 + mf][nh * 2 + nf] = __builtin_amdgcn_mfma_f32_16x16x32_bf16(
                a_[mf][kk], b_[nf][kk], acc[mh * 4 + mf][nh * 2 + nf], 0, 0, 0);
      __builtin_amdgcn_s_setprio(0);
    }
    __builtin_amdgcn_s_barrier();  // reads of buf b done; safe to restage
    b ^= 1;
  }

#pragma unroll
  for (int nf = 0; nf < 4; nf++) {
    const int col = n0 + wn * 64 + nf * 16 + l16;
    const float bj = bias[col];
#pragma unroll
    for (int mf = 0; mf < 8; mf++) {
      const int rowb = m0 + wm * 128 + mf * 16 + quad * 4;
#pragma unroll
      for (int r = 0; r < 4; r++) {
        float v = acc[mf][nf][r] + bj;
        if (RELU) v = v > 0.f ? v : 0.f;
        outb[(size_t)(rowb + r) * N + col] = f2bf(v);
      }
    }
  }
}

// ---------------------------------------------------------------------------
// GEMM: C[M,N] = A[M,K] @ W[N,K]^T (+ bias[N]) (A,W bf16; C bf16/f32)
// BMx128 tile, BK=32, 4 waves 2x2 (r4-proven config for Wo/W2 whose
// N=1024 gives bad fill at 256^2 tiles). __launch_bounds__(256,3).
// ---------------------------------------------------------------------------
template <int BM, bool RELU, bool OUT_BF16, bool BIAS>
__global__ __launch_bounds__(256, 3) void gemm_bt(
    const unsigned short* __restrict__ A, const unsigned short* __restrict__ W,
    const float* __restrict__ bias, unsigned short* __restrict__ outb,
    float* __restrict__ outf, float* __restrict__ outf2, int M, int N, int K) {
  constexpr int MI = BM / 32;   // mfma m-tiles per wave (4 or 2)
  constexpr int ACP = BM / 64;  // A staging copies (2 or 1)
  const int tid = threadIdx.x;
  const int wave = tid >> 6, lane = tid & 63;
  const int quad = lane >> 4, l16 = lane & 15;
  const int wm = wave & 1, wn = wave >> 1;

  const int gx = gridDim.x, gy = gridDim.y, gz = gridDim.z;
  int bx = blockIdx.x, by = blockIdx.y, bz = blockIdx.z;
  if ((gy & 7) == 0) {
    const int i = blockIdx.x + gx * (blockIdx.y + gy * blockIdx.z);
    const int g = i & 7, s = i >> 3;
    const int yg = gy >> 3;
    by = g * yg + (s % yg);
    const int rem = s / yg;
    bx = rem % gx;
    bz = rem / gx;
  }
  const int m0 = by * BM, n0 = bx * 128;
  const int kz = bz;
  const int Kh = K / gz;
  const int kof = kz * Kh;

  __shared__ __align__(16) unsigned short As[2][BM * 32];
  __shared__ __align__(16) unsigned short Bs[2][128 * 32];

  const int r0 = tid >> 2;
  const int kc = (tid & 3) * 8;
  const unsigned short* Ag[ACP];
#pragma unroll
  for (int i = 0; i < ACP; i++)
    Ag[i] = A + (size_t)(m0 + r0 + 64 * i) * K + kof + kc;
  const unsigned short* Bg[2];
#pragma unroll
  for (int i = 0; i < 2; i++)
    Bg[i] = W + (size_t)(n0 + r0 + 64 * i) * K + kof + kc;

  f32x4 acc[MI][4];
#pragma unroll
  for (int i = 0; i < MI; i++)
#pragma unroll
    for (int j = 0; j < 4; j++) acc[i][j] = (f32x4){0.f, 0.f, 0.f, 0.f};

  auto stage = [&](int koff, int bsel) {
#pragma unroll
    for (int i = 0; i < ACP; i++)
      async_copy16(Ag[i] + koff, &As[bsel][(i * 256 + wave * 64) * 8]);
#pragma unroll
    for (int i = 0; i < 2; i++)
      async_copy16(Bg[i] + koff, &Bs[bsel][(i * 256 + wave * 64) * 8]);
  };

  stage(0, 0);
  int buf = 0;
  for (int k0 = 0; k0 < Kh; k0 += 32) {
    __syncthreads();
    if (k0 + 32 < Kh) stage(k0 + 32, buf ^ 1);
    bf16x8 af[MI], bfr[4];
#pragma unroll
    for (int i = 0; i < MI; i++)
      af[i] =
          *(const bf16x8*)&As[buf][(wm * (MI * 16) + i * 16 + l16) * 32 + quad * 8];
#pragma unroll
    for (int j = 0; j < 4; j++)
      bfr[j] = *(const bf16x8*)&Bs[buf][(wn * 64 + j * 16 + l16) * 32 + quad * 8];
#pragma unroll
    for (int i = 0; i < MI; i++)
#pragma unroll
      for (int j = 0; j < 4; j++)
        acc[i][j] =
            __builtin_amdgcn_mfma_f32_16x16x32_bf16(af[i], bfr[j], acc[i][j], 0, 0, 0);
    buf ^= 1;
  }

  float* outp = (outf2 != nullptr && kz == gz - 1) ? outf2
                                                   : outf + (size_t)kz * M * N;
#pragma unroll
  for (int j = 0; j < 4; j++) {
    const int col = n0 + wn * 64 + j * 16 + l16;
    const float bj = BIAS ? bias[col] : 0.f;
#pragma unroll
    for (int i = 0; i < MI; i++) {
      const int rowb = m0 + wm * (MI * 16) + i * 16 + quad * 4;
#pragma unroll
      for (int r = 0; r < 4; r++) {
        float v = acc[i][j][r] + bj;
        if (RELU) v = v > 0.f ? v : 0.f;
        const size_t idx = (size_t)(rowb + r) * N + col;
        if (OUT_BF16) outb[idx] = f2bf(v);
        else outp[idx] = v;
      }
    }
  }
}

// ---------------------------------------------------------------------------
// MFMA flash attention, causal (r4-proven version, EXACT: single-buffered
// K/V, in-kernel scalar V transpose, 27.6 KB LDS -> 4 blocks/CU, T5
// setprio + T13 defer-max). Run-to-run noise on this kernel is ~±4 us.
// ---------------------------------------------------------------------------
__global__ __launch_bounds__(256, 4) void attn_mfma(
    const unsigned short* __restrict__ qkv, unsigned short* __restrict__ out) {
  const int tid = threadIdx.x;
  const int w = tid >> 6, lane = tid & 63;
  const int quad = lane >> 4, l16 = lane & 15;
  const int bh = blockIdx.x;
  const int b = bh >> 4, h = bh & 15;
  const int y = blockIdx.y;
  const int t = (y < 8) ? (31 - y) : (y < 16) ? (y - 8) : (y < 24) ? (39 - y)
                                                                   : (y - 16);
  const int qwb = t * 64 + w * 16;  // wave's first q row

  __shared__ __align__(16) unsigned short Ks[64 * 72];     // [k][d]
  __shared__ __align__(16) unsigned short Vt[64 * 72];     // [d][k-swizzled]
  __shared__ __align__(16) unsigned short Pw[4][16 * 72];  // per-wave P [q][k]

  // Q B-frags (x0.125 folded, exact)
  bf16x8 qb[2];
#pragma unroll
  for (int kd = 0; kd < 2; kd++) {
    const unsigned short* qp =
        qkv + (size_t)(b * NL + qwb + l16) * (3 * ND) + h * NDH + kd * 32 + quad * 8;
    union { uint4 u; unsigned short s[8]; bf16x8 v; } qu;
    qu.u = *(const uint4*)qp;
#pragma unroll
    for (int e = 0; e < 8; e++) qu.s[e] = f2bf(bf2f(qu.s[e]) * 0.125f);
    qb[kd] = qu.v;
  }

  float m_s = -INFINITY, l_s = 0.f;
  f32x4 of_[4];
#pragma unroll
  for (int nd = 0; nd < 4; nd++) of_[nd] = (f32x4){0.f, 0.f, 0.f, 0.f};

  const int nch = t + 1;
  for (int c = 0; c < nch; c++) {
    const int kbase = c * 64;
    __syncthreads();
#pragma unroll
    for (int p = 0; p < 2; p++) {
      const int kk = p * 32 + (tid >> 3);
      const int d0 = (tid & 7) * 8;
      const unsigned short* gk =
          qkv + (size_t)(b * NL + kbase + kk) * (3 * ND) + ND + h * NDH + d0;
      uint4 ku = *(const uint4*)gk;
      uint4 vu = *(const uint4*)(gk + ND);
      *(uint4*)&Ks[kk * 72 + d0] = ku;
      const unsigned short* pv = (const unsigned short*)&vu;
      const int kg = kk >> 3, kr = kk & 7;
#pragma unroll
      for (int e = 0; e < 8; e++) {
        const int d = d0 + e;
        Vt[d * 72 + ((kg ^ (d >> 3)) & 7) * 8 + kr] = pv[e];
      }
    }
    __syncthreads();

    f32x4 st[4];
#pragma unroll
    for (int kt = 0; kt < 4; kt++) st[kt] = (f32x4){0.f, 0.f, 0.f, 0.f};
    __builtin_amdgcn_s_setprio(1);
#pragma unroll
    for (int kd = 0; kd < 2; kd++)
#pragma unroll
      for (int kt = 0; kt < 4; kt++) {
        const bf16x8 kaf =
            *(const bf16x8*)&Ks[(kt * 16 + l16) * 72 + kd * 32 + quad * 8];
        st[kt] = __builtin_amdgcn_mfma_f32_16x16x32_bf16(kaf, qb[kd], st[kt], 0, 0, 0);
      }
    __builtin_amdgcn_s_setprio(0);

    if (kbase + 63 > qwb) {
      const int qg_ = qwb + l16;
#pragma unroll
      for (int kt = 0; kt < 4; kt++) {
        const int kg_ = kbase + kt * 16 + quad * 4;
#pragma unroll
        for (int r = 0; r < 4; r++)
          if (kg_ + r > qg_) st[kt][r] = -INFINITY;
      }
    }

    float mx = -INFINITY;
#pragma unroll
    for (int kt = 0; kt < 4; kt++)
#pragma unroll
      for (int r = 0; r < 4; r++) mx = fmaxf(mx, st[kt][r]);
    mx = fmaxf(mx, __shfl_xor(mx, 16, 64));
    mx = fmaxf(mx, __shfl_xor(mx, 32, 64));
    if (!__all(mx <= m_s + 8.f)) {
      const float mnew = fmaxf(m_s, mx);
      const float al = __expf(m_s - mnew);
      m_s = mnew;
      l_s *= al;
#pragma unroll
      for (int r = 0; r < 4; r++) {
        const float ar = __shfl(al, quad * 4 + r, 16);
#pragma unroll
        for (int nd = 0; nd < 4; nd++) of_[nd][r] *= ar;
      }
    }
    float sum = 0.f;
#pragma unroll
    for (int kt = 0; kt < 4; kt++) {
      ushort4 pk_;
#pragma unroll
      for (int r = 0; r < 4; r++) {
        const float pv_ = __expf(st[kt][r] - m_s);
        sum += pv_;
        ((unsigned short*)&pk_)[r] = f2bf(pv_);
      }
      *(ushort4*)&Pw[w][l16 * 72 + kt * 16 + quad * 4] = pk_;
    }
    sum += __shfl_xor(sum, 16, 64);
    sum += __shfl_xor(sum, 32, 64);
    l_s += sum;

    __builtin_amdgcn_s_setprio(1);
#pragma unroll
    for (int kk = 0; kk < 2; kk++) {
      const bf16x8 pa = *(const bf16x8*)&Pw[w][l16 * 72 + kk * 32 + quad * 8];
#pragma unroll
      for (int nd = 0; nd < 4; nd++) {
        const int d = nd * 16 + l16;
        const bf16x8 vbf =
            *(const bf16x8*)&Vt[d * 72 + (((kk * 4 + quad) ^ (d >> 3)) & 7) * 8];
        of_[nd] = __builtin_amdgcn_mfma_f32_16x16x32_bf16(pa, vbf, of_[nd], 0, 0, 0);
      }
    }
    __builtin_amdgcn_s_setprio(0);
  }

  const float li = 1.f / l_s;
#pragma unroll
  for (int r = 0; r < 4; r++) {
    const float lr = __shfl(li, quad * 4 + r, 16);
    const size_t rowoff = (size_t)(b * NL + qwb + quad * 4 + r) * ND + h * NDH;
#pragma unroll
    for (int nd = 0; nd < 4; nd++)
      out[rowoff + nd * 16 + l16] = f2bf(of_[nd][r] * lr);
  }
}

// ---------------------------------------------------------------------------
// (sum of NP partials + bias + res) -> LayerNorm (ddof=1). All f32.
// No __restrict__: p3 may alias of (d_out), block-local read-before-write.
// ---------------------------------------------------------------------------
__device__ __forceinline__ float block_sum256(float v, float* sbuf) {
#pragma unroll
  for (int off = 32; off > 0; off >>= 1) v += __shfl_down(v, off, 64);
  const int tid = threadIdx.x;
  if ((tid & 63) == 0) sbuf[tid >> 6] = v;
  __syncthreads();
  return sbuf[0] + sbuf[1] + sbuf[2] + sbuf[3];
}

template <bool WRITE_BF16, int NP>
__global__ __launch_bounds__(256, 4) void add_ln_kernel(
    const float* p0, const float* p1, const float* p2, const float* p3,
    const float* bias, const float* res, const float* gam, const float* bet,
    float* of, unsigned short* ob) {
  const int row = blockIdx.x, tid = threadIdx.x;
  __shared__ float sbuf[4];
  const size_t base = (size_t)row * ND;
  float x[4];
#pragma unroll
  for (int e = 0; e < 4; e++) {
    const int idx = tid + 256 * e;
    float v = p0[base + idx] + bias[idx] + res[base + idx];
    if (NP >= 2) v += p1[base + idx];
    if (NP > 2) v += p2[base + idx] + p3[base + idx];
    x[e] = v;
  }
  float s = x[0] + x[1] + x[2] + x[3];
  s = block_sum256(s, sbuf);
  const float mean = s * (1.f / (float)ND);
  float sq = 0.f;
#pragma unroll
  for (int e = 0; e < 4; e++) {
    const float d = x[e] - mean;
    sq += d * d;
  }
  __syncthreads();
  sq = block_sum256(sq, sbuf);
  const float inv = 1.f / (sqrtf(sq * (1.f / (float)(ND - 1))) + 1e-6f);
#pragma unroll
  for (int e = 0; e < 4; e++) {
    const int idx = tid + 256 * e;
    const float y = (x[e] - mean) * inv * gam[idx] + bet[idx];
    of[base + idx] = y;
    if (WRITE_BF16) ob[base + idx] = f2bf(y);
  }
}

// ---------------------------------------------------------------------------
extern "C" void kernel_launch(void* const* d_in, const int* in_sizes, int n_in,
                              void* d_out, int out_size, void* d_ws, size_t ws_size,
                              hipStream_t stream) {
  const float* x = (const float*)d_in[0];
  // d_in[1] = mask (int32) — exactly causal, handled analytically
  const float* Wqkv = (const float*)d_in[2];
  const float* bqkv = (const float*)d_in[3];
  const float* Wo = (const float*)d_in[4];
  const float* bo = (const float*)d_in[5];
  const float* ln1a = (const float*)d_in[6];
  const float* ln1b = (const float*)d_in[7];
  const float* W1 = (const float*)d_in[8];
  const float* b1 = (const float*)d_in[9];
  const float* W2 = (const float*)d_in[10];
  const float* b2 = (const float*)d_in[11];
  const float* ln2a = (const float*)d_in[12];
  const float* ln2b = (const float*)d_in[13];

  // workspace layout (MiB); peak 112 (r4-proven layout, unchanged)
  char* ws = (char*)d_ws;
  unsigned short* qkv = (unsigned short*)(ws);
  unsigned short* ffn1 = (unsigned short*)(ws);
  unsigned short* Wqkvb = (unsigned short*)(ws + 25165824);
  unsigned short* aout = (unsigned short*)(ws + 25165824);
  unsigned short* xb = (unsigned short*)(ws + 33554432);
  float* pWo = (float*)(ws + 33554432);
  float* pW2 = (float*)(ws + 33554432);
  unsigned short* Wob = (unsigned short*)(ws + 67108864);
  unsigned short* W1b = (unsigned short*)(ws + 69206016);
  float* hf = (float*)(ws + 83886080);
  unsigned short* hb = (unsigned short*)(ws + 100663296);
  unsigned short* W2b = (unsigned short*)(ws + 109051904);

  const int M = NB * NL;  // 4096
  const size_t MN = (size_t)M * ND;
  dim3 blk(256);

  // 0) all f32->bf16 casts in one launch
  cast_all<<<dim3(16384), blk, 0, stream>>>(x, Wqkv, Wo, W1, W2, xb, Wqkvb, Wob,
                                            W1b, W2b);
  // 1) qkv = x @ Wqkv^T + bqkv -> bf16 (256^2 8-phase: 12x16 = 192 blocks)
  gemm256<false><<<dim3(3 * ND / 256, M / 256), dim3(512), 0, stream>>>(
      xb, Wqkvb, bqkv, qkv, M, 3 * ND, ND);
  // 2) attention -> aout bf16 (64-row q-tiles, 1024 blocks, long-first order)
  attn_mfma<<<dim3(NB * NH, NL / 64), blk, 0, stream>>>(qkv, aout);
  // 3) Wo partials (BM=64, split-K x2 -> 1024 blocks): pWo + z*M*N
  gemm_bt<64, false, false, false><<<dim3(ND / 128, M / 64, 2), blk, 0, stream>>>(
      aout, Wob, nullptr, nullptr, pWo, nullptr, M, ND, ND);
  // 4) h = LN(x + p0 + p1 + bo) -> hf (f32) + hb (bf16)
  add_ln_kernel<true, 2><<<dim3(M), blk, 0, stream>>>(
      pWo, pWo + MN, pWo, pWo, bo, x, ln1a, ln1b, hf, hb);
  // 5) ffn1 = relu(h @ W1^T + b1) -> bf16 (256^2 8-phase: 16x16 = 256 blocks)
  gemm256<true><<<dim3(NDFF / 256, M / 256), dim3(512), 0, stream>>>(
      hb, W1b, b1, ffn1, M, NDFF, ND);
  // 6) W2 partials (BM=128, split-K x4 -> 1024 blocks):
  //    slots 0-2 in pW2, slot 3 in d_out
  gemm_bt<128, false, false, false><<<dim3(ND / 128, M / 128, 4), blk, 0, stream>>>(
      ffn1, W2b, nullptr, nullptr, pW2, (float*)d_out, M, ND, NDFF);
  // 7) out = LN(hf + p0+p1+p2+p3 + b2) -> f32 d_out (p3 aliases d_out: safe)
  add_ln_kernel<false, 4><<<dim3(M), blk, 0, stream>>>(
      pW2, pW2 + MN, pW2 + 2 * MN, (float*)d_out, b2, hf, ln2a, ln2b,
      (float*)d_out, nullptr);
}

// Round 11
// 357.954 us; speedup vs baseline: 1.0160x; 1.0160x over previous
//
#include <hip/hip_runtime.h>
#include <cstdint>
#include <cstddef>

#define NB 2
#define NL 2048
#define ND 1024
#define NH 16
#define NDH 64
#define NDFF 4096

typedef __bf16 bf16_t;
typedef bf16_t bf16x8 __attribute__((ext_vector_type(8)));
typedef float f32x4 __attribute__((ext_vector_type(4)));

__device__ __forceinline__ float bf2f(unsigned short h) {
  union { unsigned u; float f; } c; c.u = ((unsigned)h) << 16; return c.f;
}
__device__ __forceinline__ unsigned short f2bf(float f) {
  union { float f; unsigned u; } c; c.f = f;
  return (unsigned short)((c.u + 0x7fffu + ((c.u >> 16) & 1u)) >> 16);
}

// async global->LDS, 16B per lane; lds base must be wave-uniform.
__device__ __forceinline__ void async_copy16(const void* g, void* l) {
  __builtin_amdgcn_global_load_lds(
      (const __attribute__((address_space(1))) void*)g,
      (__attribute__((address_space(3))) void*)l, 16, 0, 0);
}

// ---------------------------------------------------------------------------
// Fused f32 -> bf16 cast of x + all 4 weight matrices, one launch.
// ---------------------------------------------------------------------------
__global__ __launch_bounds__(256) void cast_all(
    const float* __restrict__ x, const float* __restrict__ wqkv,
    const float* __restrict__ wo, const float* __restrict__ w1,
    const float* __restrict__ w2, unsigned short* __restrict__ xb,
    unsigned short* __restrict__ wqkvb, unsigned short* __restrict__ wob,
    unsigned short* __restrict__ w1b, unsigned short* __restrict__ w2b) {
  const int i = blockIdx.x * 256 + threadIdx.x;
  const float* src;
  unsigned short* dst;
  int off;
  if (i < 1048576) { src = x; dst = xb; off = i; }  // 4M elems (vec4)
  else if (i < 1835008) { src = wqkv; dst = wqkvb; off = i - 1048576; }
  else if (i < 2097152) { src = wo; dst = wob; off = i - 1835008; }
  else if (i < 3145728) { src = w1; dst = w1b; off = i - 2097152; }
  else { src = w2; dst = w2b; off = i - 3145728; }
  const float4 v = ((const float4*)src)[off];
  ushort4 o;
  o.x = f2bf(v.x); o.y = f2bf(v.y); o.z = f2bf(v.z); o.w = f2bf(v.w);
  ((ushort4*)dst)[off] = o;
}

// ---------------------------------------------------------------------------
// 256x256 8-wave GEMM, BK=64 (verified-correct r10 port; used ONLY where
// the grid fills the machine: ffn1 = 16x16 = 256 blocks at 1/CU).
// r10 lesson: qkv at 192 blocks left 25% of CUs idle -> +13 us; shape fit,
// not structure, was the regression. Schedule per K-tile: {stage next tile
// (8 global_load_lds); vmcnt(8) COUNTED (waits only on loads issued a full
// K-tile ago); raw s_barrier (no implicit vmcnt(0) drain); 4 phases x
// {12 ds_read_b128, setprio(1), 16 MFMA, setprio(0)}; s_barrier}.
// Swizzle (rule #21, both-sides): linear LDS dest, global SOURCE granule
// pre-XOR'd by (row&7), ds_read address XOR'd the same -> 8 lanes per
// 4-bank granule group = uniform, conflict-free b128 reads.
// ---------------------------------------------------------------------------
template <bool RELU>
__global__ __launch_bounds__(512, 2) void gemm256(
    const unsigned short* __restrict__ A, const unsigned short* __restrict__ W,
    const float* __restrict__ bias, unsigned short* __restrict__ outb,
    int M, int N, int K) {
  const int tid = threadIdx.x;
  const int lane = tid & 63;
  const int wid = tid >> 6;
  const int wm = wid >> 2, wn = wid & 3;
  const int quad = lane >> 4, l16 = lane & 15;

  // XCD-aware remap (gy multiple of 8)
  const int gx = gridDim.x, gy = gridDim.y;
  int bx = blockIdx.x, by = blockIdx.y;
  if ((gy & 7) == 0) {
    const int i = blockIdx.x + gx * blockIdx.y;
    const int g = i & 7, s = i >> 3;
    const int yg = gy >> 3;
    by = g * yg + (s % yg);
    bx = (s / yg) % gx;
  }
  const int m0 = by * 256, n0 = bx * 256;

  __shared__ __align__(16) unsigned short As[2][256 * 64];
  __shared__ __align__(16) unsigned short Bs[2][256 * 64];

  // staging: load l covers row l*64 + (tid>>3); source granule pre-swizzled
  const int srow = tid >> 3;                 // 0..63
  const int gsrc = (tid & 7) ^ (srow & 7);   // logical granule for this slot
  const unsigned short* Ag = A + (size_t)(m0 + srow) * K + gsrc * 8;
  const unsigned short* Bg = W + (size_t)(n0 + srow) * K + gsrc * 8;
  const int ldst = srow * 64 + (tid & 7) * 8;  // linear LDS elem offset

  f32x4 acc[8][4];
#pragma unroll
  for (int i = 0; i < 8; i++)
#pragma unroll
    for (int j = 0; j < 4; j++) acc[i][j] = (f32x4){0.f, 0.f, 0.f, 0.f};

  auto stage = [&](int kt, int bsel) {
#pragma unroll
    for (int l = 0; l < 4; l++)
      async_copy16(Ag + (size_t)(l * 64) * K + kt * 64,
                   &As[bsel][l * 64 * 64 + ldst]);
#pragma unroll
    for (int l = 0; l < 4; l++)
      async_copy16(Bg + (size_t)(l * 64) * K + kt * 64,
                   &Bs[bsel][l * 64 * 64 + ldst]);
  };

  // read-side addressing: row&7 == l16&7 for both A and B fragments
  const int arow = wm * 128 + l16;  // + mf*16
  const int brow = wn * 64 + l16;   // + nf*16
  const int r7 = l16 & 7;

  const int NT = K >> 6;
  int b = 0;
  stage(0, 0);
  for (int kt = 0; kt < NT; kt++) {
    if (kt + 1 < NT) {
      stage(kt + 1, b ^ 1);  // 8 more loads in flight
      asm volatile("s_waitcnt vmcnt(8)" ::: "memory");  // this tile's done
    } else {
      asm volatile("s_waitcnt vmcnt(0)" ::: "memory");
    }
    __builtin_amdgcn_s_barrier();  // all waves' staging visible

#pragma unroll
    for (int ph = 0; ph < 4; ph++) {
      const int mh = ph >> 1, nh = ph & 1;
      bf16x8 a_[4][2], b_[2][2];
#pragma unroll
      for (int mf = 0; mf < 4; mf++)
#pragma unroll
        for (int kk = 0; kk < 2; kk++)
          a_[mf][kk] = *(const bf16x8*)&As[b][(arow + (mh * 4 + mf) * 16) * 64 +
                                             (((quad + kk * 4) ^ r7) * 8)];
#pragma unroll
      for (int nf = 0; nf < 2; nf++)
#pragma unroll
        for (int kk = 0; kk < 2; kk++)
          b_[nf][kk] = *(const bf16x8*)&Bs[b][(brow + (nh * 2 + nf) * 16) * 64 +
                                             (((quad + kk * 4) ^ r7) * 8)];
      __builtin_amdgcn_s_setprio(1);
#pragma unroll
      for (int mf = 0; mf < 4; mf++)
#pragma unroll
        for (int nf = 0; nf < 2; nf++)
#pragma unroll
          for (int kk = 0; kk < 2; kk++)
            acc[mh * 4 + mf][nh * 2 + nf] = __builtin_amdgcn_mfma_f32_16x16x32_bf16(
                a_[mf][kk], b_[nf][kk], acc[mh * 4 + mf][nh * 2 + nf], 0, 0, 0);
      __builtin_amdgcn_s_setprio(0);
    }
    __builtin_amdgcn_s_barrier();  // reads of buf b done; safe to restage
    b ^= 1;
  }

#pragma unroll
  for (int nf = 0; nf < 4; nf++) {
    const int col = n0 + wn * 64 + nf * 16 + l16;
    const float bj = bias[col];
#pragma unroll
    for (int mf = 0; mf < 8; mf++) {
      const int rowb = m0 + wm * 128 + mf * 16 + quad * 4;
#pragma unroll
      for (int r = 0; r < 4; r++) {
        float v = acc[mf][nf][r] + bj;
        if (RELU) v = v > 0.f ? v : 0.f;
        outb[(size_t)(rowb + r) * N + col] = f2bf(v);
      }
    }
  }
}

// ---------------------------------------------------------------------------
// GEMM: C[M,N] = A[M,K] @ W[N,K]^T (+ bias[N]) (A,W bf16; C bf16/f32)
// BMx128 tile, BK=32, 4 waves 2x2 (r4-proven config — used for qkv
// (768 blocks, 3/CU), Wo, and W2 whose shapes fill poorly at 256^2).
// ---------------------------------------------------------------------------
template <int BM, bool RELU, bool OUT_BF16, bool BIAS>
__global__ __launch_bounds__(256, 3) void gemm_bt(
    const unsigned short* __restrict__ A, const unsigned short* __restrict__ W,
    const float* __restrict__ bias, unsigned short* __restrict__ outb,
    float* __restrict__ outf, float* __restrict__ outf2, int M, int N, int K) {
  constexpr int MI = BM / 32;   // mfma m-tiles per wave (4 or 2)
  constexpr int ACP = BM / 64;  // A staging copies (2 or 1)
  const int tid = threadIdx.x;
  const int wave = tid >> 6, lane = tid & 63;
  const int quad = lane >> 4, l16 = lane & 15;
  const int wm = wave & 1, wn = wave >> 1;

  const int gx = gridDim.x, gy = gridDim.y, gz = gridDim.z;
  int bx = blockIdx.x, by = blockIdx.y, bz = blockIdx.z;
  if ((gy & 7) == 0) {
    const int i = blockIdx.x + gx * (blockIdx.y + gy * blockIdx.z);
    const int g = i & 7, s = i >> 3;
    const int yg = gy >> 3;
    by = g * yg + (s % yg);
    const int rem = s / yg;
    bx = rem % gx;
    bz = rem / gx;
  }
  const int m0 = by * BM, n0 = bx * 128;
  const int kz = bz;
  const int Kh = K / gz;
  const int kof = kz * Kh;

  __shared__ __align__(16) unsigned short As[2][BM * 32];
  __shared__ __align__(16) unsigned short Bs[2][128 * 32];

  const int r0 = tid >> 2;
  const int kc = (tid & 3) * 8;
  const unsigned short* Ag[ACP];
#pragma unroll
  for (int i = 0; i < ACP; i++)
    Ag[i] = A + (size_t)(m0 + r0 + 64 * i) * K + kof + kc;
  const unsigned short* Bg[2];
#pragma unroll
  for (int i = 0; i < 2; i++)
    Bg[i] = W + (size_t)(n0 + r0 + 64 * i) * K + kof + kc;

  f32x4 acc[MI][4];
#pragma unroll
  for (int i = 0; i < MI; i++)
#pragma unroll
    for (int j = 0; j < 4; j++) acc[i][j] = (f32x4){0.f, 0.f, 0.f, 0.f};

  auto stage = [&](int koff, int bsel) {
#pragma unroll
    for (int i = 0; i < ACP; i++)
      async_copy16(Ag[i] + koff, &As[bsel][(i * 256 + wave * 64) * 8]);
#pragma unroll
    for (int i = 0; i < 2; i++)
      async_copy16(Bg[i] + koff, &Bs[bsel][(i * 256 + wave * 64) * 8]);
  };

  stage(0, 0);
  int buf = 0;
  for (int k0 = 0; k0 < Kh; k0 += 32) {
    __syncthreads();
    if (k0 + 32 < Kh) stage(k0 + 32, buf ^ 1);
    bf16x8 af[MI], bfr[4];
#pragma unroll
    for (int i = 0; i < MI; i++)
      af[i] =
          *(const bf16x8*)&As[buf][(wm * (MI * 16) + i * 16 + l16) * 32 + quad * 8];
#pragma unroll
    for (int j = 0; j < 4; j++)
      bfr[j] = *(const bf16x8*)&Bs[buf][(wn * 64 + j * 16 + l16) * 32 + quad * 8];
#pragma unroll
    for (int i = 0; i < MI; i++)
#pragma unroll
      for (int j = 0; j < 4; j++)
        acc[i][j] =
            __builtin_amdgcn_mfma_f32_16x16x32_bf16(af[i], bfr[j], acc[i][j], 0, 0, 0);
    buf ^= 1;
  }

  float* outp = (outf2 != nullptr && kz == gz - 1) ? outf2
                                                   : outf + (size_t)kz * M * N;
#pragma unroll
  for (int j = 0; j < 4; j++) {
    const int col = n0 + wn * 64 + j * 16 + l16;
    const float bj = BIAS ? bias[col] : 0.f;
#pragma unroll
    for (int i = 0; i < MI; i++) {
      const int rowb = m0 + wm * (MI * 16) + i * 16 + quad * 4;
#pragma unroll
      for (int r = 0; r < 4; r++) {
        float v = acc[i][j][r] + bj;
        if (RELU) v = v > 0.f ? v : 0.f;
        const size_t idx = (size_t)(rowb + r) * N + col;
        if (OUT_BF16) outb[idx] = f2bf(v);
        else outp[idx] = v;
      }
    }
  }
}

// ---------------------------------------------------------------------------
// MFMA flash attention, causal (r4-proven version, EXACT: single-buffered
// K/V, in-kernel scalar V transpose, 27.6 KB LDS -> 4 blocks/CU, T5
// setprio + T13 defer-max). Run-to-run noise on this kernel is ~±4 us.
// ---------------------------------------------------------------------------
__global__ __launch_bounds__(256, 4) void attn_mfma(
    const unsigned short* __restrict__ qkv, unsigned short* __restrict__ out) {
  const int tid = threadIdx.x;
  const int w = tid >> 6, lane = tid & 63;
  const int quad = lane >> 4, l16 = lane & 15;
  const int bh = blockIdx.x;
  const int b = bh >> 4, h = bh & 15;
  const int y = blockIdx.y;
  const int t = (y < 8) ? (31 - y) : (y < 16) ? (y - 8) : (y < 24) ? (39 - y)
                                                                   : (y - 16);
  const int qwb = t * 64 + w * 16;  // wave's first q row

  __shared__ __align__(16) unsigned short Ks[64 * 72];     // [k][d]
  __shared__ __align__(16) unsigned short Vt[64 * 72];     // [d][k-swizzled]
  __shared__ __align__(16) unsigned short Pw[4][16 * 72];  // per-wave P [q][k]

  // Q B-frags (x0.125 folded, exact)
  bf16x8 qb[2];
#pragma unroll
  for (int kd = 0; kd < 2; kd++) {
    const unsigned short* qp =
        qkv + (size_t)(b * NL + qwb + l16) * (3 * ND) + h * NDH + kd * 32 + quad * 8;
    union { uint4 u; unsigned short s[8]; bf16x8 v; } qu;
    qu.u = *(const uint4*)qp;
#pragma unroll
    for (int e = 0; e < 8; e++) qu.s[e] = f2bf(bf2f(qu.s[e]) * 0.125f);
    qb[kd] = qu.v;
  }

  float m_s = -INFINITY, l_s = 0.f;
  f32x4 of_[4];
#pragma unroll
  for (int nd = 0; nd < 4; nd++) of_[nd] = (f32x4){0.f, 0.f, 0.f, 0.f};

  const int nch = t + 1;
  for (int c = 0; c < nch; c++) {
    const int kbase = c * 64;
    __syncthreads();
#pragma unroll
    for (int p = 0; p < 2; p++) {
      const int kk = p * 32 + (tid >> 3);
      const int d0 = (tid & 7) * 8;
      const unsigned short* gk =
          qkv + (size_t)(b * NL + kbase + kk) * (3 * ND) + ND + h * NDH + d0;
      uint4 ku = *(const uint4*)gk;
      uint4 vu = *(const uint4*)(gk + ND);
      *(uint4*)&Ks[kk * 72 + d0] = ku;
      const unsigned short* pv = (const unsigned short*)&vu;
      const int kg = kk >> 3, kr = kk & 7;
#pragma unroll
      for (int e = 0; e < 8; e++) {
        const int d = d0 + e;
        Vt[d * 72 + ((kg ^ (d >> 3)) & 7) * 8 + kr] = pv[e];
      }
    }
    __syncthreads();

    f32x4 st[4];
#pragma unroll
    for (int kt = 0; kt < 4; kt++) st[kt] = (f32x4){0.f, 0.f, 0.f, 0.f};
    __builtin_amdgcn_s_setprio(1);
#pragma unroll
    for (int kd = 0; kd < 2; kd++)
#pragma unroll
      for (int kt = 0; kt < 4; kt++) {
        const bf16x8 kaf =
            *(const bf16x8*)&Ks[(kt * 16 + l16) * 72 + kd * 32 + quad * 8];
        st[kt] = __builtin_amdgcn_mfma_f32_16x16x32_bf16(kaf, qb[kd], st[kt], 0, 0, 0);
      }
    __builtin_amdgcn_s_setprio(0);

    if (kbase + 63 > qwb) {
      const int qg_ = qwb + l16;
#pragma unroll
      for (int kt = 0; kt < 4; kt++) {
        const int kg_ = kbase + kt * 16 + quad * 4;
#pragma unroll
        for (int r = 0; r < 4; r++)
          if (kg_ + r > qg_) st[kt][r] = -INFINITY;
      }
    }

    float mx = -INFINITY;
#pragma unroll
    for (int kt = 0; kt < 4; kt++)
#pragma unroll
      for (int r = 0; r < 4; r++) mx = fmaxf(mx, st[kt][r]);
    mx = fmaxf(mx, __shfl_xor(mx, 16, 64));
    mx = fmaxf(mx, __shfl_xor(mx, 32, 64));
    if (!__all(mx <= m_s + 8.f)) {
      const float mnew = fmaxf(m_s, mx);
      const float al = __expf(m_s - mnew);
      m_s = mnew;
      l_s *= al;
#pragma unroll
      for (int r = 0; r < 4; r++) {
        const float ar = __shfl(al, quad * 4 + r, 16);
#pragma unroll
        for (int nd = 0; nd < 4; nd++) of_[nd][r] *= ar;
      }
    }
    float sum = 0.f;
#pragma unroll
    for (int kt = 0; kt < 4; kt++) {
      ushort4 pk_;
#pragma unroll
      for (int r = 0; r < 4; r++) {
        const float pv_ = __expf(st[kt][r] - m_s);
        sum += pv_;
        ((unsigned short*)&pk_)[r] = f2bf(pv_);
      }
      *(ushort4*)&Pw[w][l16 * 72 + kt * 16 + quad * 4] = pk_;
    }
    sum += __shfl_xor(sum, 16, 64);
    sum += __shfl_xor(sum, 32, 64);
    l_s += sum;

    __builtin_amdgcn_s_setprio(1);
#pragma unroll
    for (int kk = 0; kk < 2; kk++) {
      const bf16x8 pa = *(const bf16x8*)&Pw[w][l16 * 72 + kk * 32 + quad * 8];
#pragma unroll
      for (int nd = 0; nd < 4; nd++) {
        const int d = nd * 16 + l16;
        const bf16x8 vbf =
            *(const bf16x8*)&Vt[d * 72 + (((kk * 4 + quad) ^ (d >> 3)) & 7) * 8];
        of_[nd] = __builtin_amdgcn_mfma_f32_16x16x32_bf16(pa, vbf, of_[nd], 0, 0, 0);
      }
    }
    __builtin_amdgcn_s_setprio(0);
  }

  const float li = 1.f / l_s;
#pragma unroll
  for (int r = 0; r < 4; r++) {
    const float lr = __shfl(li, quad * 4 + r, 16);
    const size_t rowoff = (size_t)(b * NL + qwb + quad * 4 + r) * ND + h * NDH;
#pragma unroll
    for (int nd = 0; nd < 4; nd++)
      out[rowoff + nd * 16 + l16] = f2bf(of_[nd][r] * lr);
  }
}

// ---------------------------------------------------------------------------
// (sum of NP partials + bias + res) -> LayerNorm (ddof=1). All f32.
// No __restrict__: p3 may alias of (d_out), block-local read-before-write.
// ---------------------------------------------------------------------------
__device__ __forceinline__ float block_sum256(float v, float* sbuf) {
#pragma unroll
  for (int off = 32; off > 0; off >>= 1) v += __shfl_down(v, off, 64);
  const int tid = threadIdx.x;
  if ((tid & 63) == 0) sbuf[tid >> 6] = v;
  __syncthreads();
  return sbuf[0] + sbuf[1] + sbuf[2] + sbuf[3];
}

template <bool WRITE_BF16, int NP>
__global__ __launch_bounds__(256, 4) void add_ln_kernel(
    const float* p0, const float* p1, const float* p2, const float* p3,
    const float* bias, const float* res, const float* gam, const float* bet,
    float* of, unsigned short* ob) {
  const int row = blockIdx.x, tid = threadIdx.x;
  __shared__ float sbuf[4];
  const size_t base = (size_t)row * ND;
  float x[4];
#pragma unroll
  for (int e = 0; e < 4; e++) {
    const int idx = tid + 256 * e;
    float v = p0[base + idx] + bias[idx] + res[base + idx];
    if (NP >= 2) v += p1[base + idx];
    if (NP > 2) v += p2[base + idx] + p3[base + idx];
    x[e] = v;
  }
  float s = x[0] + x[1] + x[2] + x[3];
  s = block_sum256(s, sbuf);
  const float mean = s * (1.f / (float)ND);
  float sq = 0.f;
#pragma unroll
  for (int e = 0; e < 4; e++) {
    const float d = x[e] - mean;
    sq += d * d;
  }
  __syncthreads();
  sq = block_sum256(sq, sbuf);
  const float inv = 1.f / (sqrtf(sq * (1.f / (float)(ND - 1))) + 1e-6f);
#pragma unroll
  for (int e = 0; e < 4; e++) {
    const int idx = tid + 256 * e;
    const float y = (x[e] - mean) * inv * gam[idx] + bet[idx];
    of[base + idx] = y;
    if (WRITE_BF16) ob[base + idx] = f2bf(y);
  }
}

// ---------------------------------------------------------------------------
extern "C" void kernel_launch(void* const* d_in, const int* in_sizes, int n_in,
                              void* d_out, int out_size, void* d_ws, size_t ws_size,
                              hipStream_t stream) {
  const float* x = (const float*)d_in[0];
  // d_in[1] = mask (int32) — exactly causal, handled analytically
  const float* Wqkv = (const float*)d_in[2];
  const float* bqkv = (const float*)d_in[3];
  const float* Wo = (const float*)d_in[4];
  const float* bo = (const float*)d_in[5];
  const float* ln1a = (const float*)d_in[6];
  const float* ln1b = (const float*)d_in[7];
  const float* W1 = (const float*)d_in[8];
  const float* b1 = (const float*)d_in[9];
  const float* W2 = (const float*)d_in[10];
  const float* b2 = (const float*)d_in[11];
  const float* ln2a = (const float*)d_in[12];
  const float* ln2b = (const float*)d_in[13];

  // workspace layout (MiB); peak 112 (r4-proven layout, unchanged)
  char* ws = (char*)d_ws;
  unsigned short* qkv = (unsigned short*)(ws);
  unsigned short* ffn1 = (unsigned short*)(ws);
  unsigned short* Wqkvb = (unsigned short*)(ws + 25165824);
  unsigned short* aout = (unsigned short*)(ws + 25165824);
  unsigned short* xb = (unsigned short*)(ws + 33554432);
  float* pWo = (float*)(ws + 33554432);
  float* pW2 = (float*)(ws + 33554432);
  unsigned short* Wob = (unsigned short*)(ws + 67108864);
  unsigned short* W1b = (unsigned short*)(ws + 69206016);
  float* hf = (float*)(ws + 83886080);
  unsigned short* hb = (unsigned short*)(ws + 100663296);
  unsigned short* W2b = (unsigned short*)(ws + 109051904);

  const int M = NB * NL;  // 4096
  const size_t MN = (size_t)M * ND;
  dim3 blk(256);

  // 0) all f32->bf16 casts in one launch
  cast_all<<<dim3(16384), blk, 0, stream>>>(x, Wqkv, Wo, W1, W2, xb, Wqkvb, Wob,
                                            W1b, W2b);
  // 1) qkv = x @ Wqkv^T + bqkv -> bf16 (128^2 proven: 24x32 = 768 blocks;
  //    r10 showed 256^2 here leaves 64 CUs idle at 192 blocks)
  gemm_bt<128, false, true, true><<<dim3(3 * ND / 128, M / 128), blk, 0, stream>>>(
      xb, Wqkvb, bqkv, qkv, nullptr, nullptr, M, 3 * ND, ND);
  // 2) attention -> aout bf16 (64-row q-tiles, 1024 blocks, long-first order)
  attn_mfma<<<dim3(NB * NH, NL / 64), blk, 0, stream>>>(qkv, aout);
  // 3) Wo partials (BM=64, split-K x2 -> 1024 blocks): pWo + z*M*N
  gemm_bt<64, false, false, false><<<dim3(ND / 128, M / 64, 2), blk, 0, stream>>>(
      aout, Wob, nullptr, nullptr, pWo, nullptr, M, ND, ND);
  // 4) h = LN(x + p0 + p1 + bo) -> hf (f32) + hb (bf16)
  add_ln_kernel<true, 2><<<dim3(M), blk, 0, stream>>>(
      pWo, pWo + MN, pWo, pWo, bo, x, ln1a, ln1b, hf, hb);
  // 5) ffn1 = relu(h @ W1^T + b1) -> bf16 (256^2: 16x16 = 256 blocks, 1/CU —
  //    the one shape where gemm256 fills perfectly; A/B vs r4's 128^2)
  gemm256<true><<<dim3(NDFF / 256, M / 256), dim3(512), 0, stream>>>(
      hb, W1b, b1, ffn1, M, NDFF, ND);
  // 6) W2 partials (BM=128, split-K x4 -> 1024 blocks):
  //    slots 0-2 in pW2, slot 3 in d_out
  gemm_bt<128, false, false, false><<<dim3(ND / 128, M / 128, 4), blk, 0, stream>>>(
      ffn1, W2b, nullptr, nullptr, pW2, (float*)d_out, M, ND, NDFF);
  // 7) out = LN(hf + p0+p1+p2+p3 + b2) -> f32 d_out (p3 aliases d_out: safe)
  add_ln_kernel<false, 4><<<dim3(M), blk, 0, stream>>>(
      pW2, pW2 + MN, pW2 + 2 * MN, (float*)d_out, b2, hf, ln2a, ln2b,
      (float*)d_out, nullptr);
}

// Round 13
// 357.031 us; speedup vs baseline: 1.0186x; 1.0026x over previous
//
#include <hip/hip_runtime.h>
#include <cstdint>
#include <cstddef>

#define NB 2
#define NL 2048
#define ND 1024
#define NH 16
#define NDH 64
#define NDFF 4096

typedef __bf16 bf16_t;
typedef bf16_t bf16x8 __attribute__((ext_vector_type(8)));
typedef float f32x4 __attribute__((ext_vector_type(4)));

__device__ __forceinline__ float bf2f(unsigned short h) {
  union { unsigned u; float f; } c; c.u = ((unsigned)h) << 16; return c.f;
}
__device__ __forceinline__ unsigned short f2bf(float f) {
  union { float f; unsigned u; } c; c.f = f;
  return (unsigned short)((c.u + 0x7fffu + ((c.u >> 16) & 1u)) >> 16);
}

// async global->LDS, 16B per lane; lds base must be wave-uniform.
__device__ __forceinline__ void async_copy16(const void* g, void* l) {
  __builtin_amdgcn_global_load_lds(
      (const __attribute__((address_space(1))) void*)g,
      (__attribute__((address_space(3))) void*)l, 16, 0, 0);
}

// ---------------------------------------------------------------------------
// Fused f32 -> bf16 cast of x + all 4 weight matrices, one launch.
// ---------------------------------------------------------------------------
__global__ __launch_bounds__(256) void cast_all(
    const float* __restrict__ x, const float* __restrict__ wqkv,
    const float* __restrict__ wo, const float* __restrict__ w1,
    const float* __restrict__ w2, unsigned short* __restrict__ xb,
    unsigned short* __restrict__ wqkvb, unsigned short* __restrict__ wob,
    unsigned short* __restrict__ w1b, unsigned short* __restrict__ w2b) {
  const int i = blockIdx.x * 256 + threadIdx.x;
  const float* src;
  unsigned short* dst;
  int off;
  if (i < 1048576) { src = x; dst = xb; off = i; }  // 4M elems (vec4)
  else if (i < 1835008) { src = wqkv; dst = wqkvb; off = i - 1048576; }
  else if (i < 2097152) { src = wo; dst = wob; off = i - 1835008; }
  else if (i < 3145728) { src = w1; dst = w1b; off = i - 2097152; }
  else { src = w2; dst = w2b; off = i - 3145728; }
  const float4 v = ((const float4*)src)[off];
  ushort4 o;
  o.x = f2bf(v.x); o.y = f2bf(v.y); o.z = f2bf(v.z); o.w = f2bf(v.w);
  ((ushort4*)dst)[off] = o;
}

// ---------------------------------------------------------------------------
// 256x256 8-wave GEMM, BK=64 (r10/r11 verified-correct; ffn1 only: 256
// blocks = 1/CU perfect fill). r11 counters: bank conflicts 0 (swizzle
// works) but WRITE_SIZE 81.6 MB for 32 MB output (2.55x): scalar bf16
// stores make 32B row-segments -> partial-line eviction. r12 fix: LDS-
// staged coalesced epilogue — acc -> LDS (stride 268: quad rows on
// disjoint bank groups 0/24/16/8), then uint4 stores (8 lanes = full
// 128B line). Main loop unchanged: stage-next + counted vmcnt(8) + raw
// s_barrier + 4 phases x {ds_read, setprio, 16 MFMA}.
// ---------------------------------------------------------------------------
template <bool RELU>
__global__ __launch_bounds__(512, 2) void gemm256(
    const unsigned short* __restrict__ A, const unsigned short* __restrict__ W,
    const float* __restrict__ bias, unsigned short* __restrict__ outb,
    int M, int N, int K) {
  const int tid = threadIdx.x;
  const int lane = tid & 63;
  const int wid = tid >> 6;
  const int wm = wid >> 2, wn = wid & 3;
  const int quad = lane >> 4, l16 = lane & 15;

  // XCD-aware remap (gy multiple of 8)
  const int gx = gridDim.x, gy = gridDim.y;
  int bx = blockIdx.x, by = blockIdx.y;
  if ((gy & 7) == 0) {
    const int i = blockIdx.x + gx * blockIdx.y;
    const int g = i & 7, s = i >> 3;
    const int yg = gy >> 3;
    by = g * yg + (s % yg);
    bx = (s / yg) % gx;
  }
  const int m0 = by * 256, n0 = bx * 256;

  __shared__ __align__(16) unsigned short smem[65536];  // 128 KiB
  unsigned short* As = smem;          // [2][256*64]
  unsigned short* Bs = smem + 32768;  // [2][256*64]

  // staging: load l covers row l*64 + (tid>>3); source granule pre-swizzled
  const int srow = tid >> 3;                 // 0..63
  const int gsrc = (tid & 7) ^ (srow & 7);   // logical granule for this slot
  const unsigned short* Ag = A + (size_t)(m0 + srow) * K + gsrc * 8;
  const unsigned short* Bg = W + (size_t)(n0 + srow) * K + gsrc * 8;
  const int ldst = srow * 64 + (tid & 7) * 8;  // linear LDS elem offset

  f32x4 acc[8][4];
#pragma unroll
  for (int i = 0; i < 8; i++)
#pragma unroll
    for (int j = 0; j < 4; j++) acc[i][j] = (f32x4){0.f, 0.f, 0.f, 0.f};

  auto stage = [&](int kt, int bsel) {
#pragma unroll
    for (int l = 0; l < 4; l++)
      async_copy16(Ag + (size_t)(l * 64) * K + kt * 64,
                   &As[bsel * 16384 + l * 64 * 64 + ldst]);
#pragma unroll
    for (int l = 0; l < 4; l++)
      async_copy16(Bg + (size_t)(l * 64) * K + kt * 64,
                   &Bs[bsel * 16384 + l * 64 * 64 + ldst]);
  };

  // read-side addressing: row&7 == l16&7 for both A and B fragments
  const int arow = wm * 128 + l16;  // + mf*16
  const int brow = wn * 64 + l16;   // + nf*16
  const int r7 = l16 & 7;

  const int NT = K >> 6;
  int b = 0;
  stage(0, 0);
  for (int kt = 0; kt < NT; kt++) {
    if (kt + 1 < NT) {
      stage(kt + 1, b ^ 1);  // 8 more loads in flight
      asm volatile("s_waitcnt vmcnt(8)" ::: "memory");  // this tile's done
    } else {
      asm volatile("s_waitcnt vmcnt(0)" ::: "memory");
    }
    __builtin_amdgcn_s_barrier();  // all waves' staging visible

#pragma unroll
    for (int ph = 0; ph < 4; ph++) {
      const int mh = ph >> 1, nh = ph & 1;
      bf16x8 a_[4][2], b_[2][2];
#pragma unroll
      for (int mf = 0; mf < 4; mf++)
#pragma unroll
        for (int kk = 0; kk < 2; kk++)
          a_[mf][kk] = *(const bf16x8*)&As[b * 16384 +
                                          (arow + (mh * 4 + mf) * 16) * 64 +
                                          (((quad + kk * 4) ^ r7) * 8)];
#pragma unroll
      for (int nf = 0; nf < 2; nf++)
#pragma unroll
        for (int kk = 0; kk < 2; kk++)
          b_[nf][kk] = *(const bf16x8*)&Bs[b * 16384 +
                                          (brow + (nh * 2 + nf) * 16) * 64 +
                                          (((quad + kk * 4) ^ r7) * 8)];
      __builtin_amdgcn_s_setprio(1);
#pragma unroll
      for (int mf = 0; mf < 4; mf++)
#pragma unroll
        for (int nf = 0; nf < 2; nf++)
#pragma unroll
          for (int kk = 0; kk < 2; kk++)
            acc[mh * 4 + mf][nh * 2 + nf] = __builtin_amdgcn_mfma_f32_16x16x32_bf16(
                a_[mf][kk], b_[nf][kk], acc[mh * 4 + mf][nh * 2 + nf], 0, 0, 0);
      __builtin_amdgcn_s_setprio(0);
    }
    __builtin_amdgcn_s_barrier();  // reads of buf b done; safe to restage
    b ^= 1;
  }

  // ---- coalesced epilogue: acc -> LDS (padded) -> uint4 global stores ----
  __syncthreads();  // all MFMA LDS reads done; smem reusable
  unsigned short* Ct = smem;  // 128 rows x 268 elems = 34304 <= 65536
#pragma unroll
  for (int h = 0; h < 2; h++) {
    if (wm == h) {
#pragma unroll
      for (int nf = 0; nf < 4; nf++) {
        const float bj = bias[n0 + wn * 64 + nf * 16 + l16];
#pragma unroll
        for (int mf = 0; mf < 8; mf++)
#pragma unroll
          for (int r = 0; r < 4; r++) {
            float v = acc[mf][nf][r] + bj;
            if (RELU) v = v > 0.f ? v : 0.f;
            Ct[(mf * 16 + quad * 4 + r) * 268 + wn * 64 + nf * 16 + l16] =
                f2bf(v);
          }
      }
    }
    __syncthreads();
#pragma unroll
    for (int i2 = 0; i2 < 8; i2++) {
      const int flat = i2 * 512 + tid;  // 4096 uint4 = 128 rows x 32
      const int row = flat >> 5, cx = flat & 31;
      *(uint4*)&outb[(size_t)(m0 + h * 128 + row) * N + n0 + cx * 8] =
          *(const uint4*)&Ct[row * 268 + cx * 8];
    }
    __syncthreads();
  }
}

// ---------------------------------------------------------------------------
// GEMM: C[M,N] = A[M,K] @ W[N,K]^T (+ bias[N]) (A,W bf16; C bf16/f32)
// BMx128 tile, BK=32, 4 waves 2x2 (r4-proven main loop). r12: OUT_BF16
// path (qkv, BM=128) gets the same LDS-staged coalesced epilogue (scalar
// bf16 stores = 32B segments = 2.5x write amplification, per r11 gemm256
// counters). f32 partial path (64B segments, no amplification) unchanged.
// ---------------------------------------------------------------------------
template <int BM, bool RELU, bool OUT_BF16, bool BIAS>
__global__ __launch_bounds__(256, 3) void gemm_bt(
    const unsigned short* __restrict__ A, const unsigned short* __restrict__ W,
    const float* __restrict__ bias, unsigned short* __restrict__ outb,
    float* __restrict__ outf, float* __restrict__ outf2, int M, int N, int K) {
  constexpr int MI = BM / 32;   // mfma m-tiles per wave (4 or 2)
  constexpr int ACP = BM / 64;  // A staging copies (2 or 1)
  static_assert(!OUT_BF16 || BM == 128, "bf16 epilogue assumes BM=128");
  const int tid = threadIdx.x;
  const int wave = tid >> 6, lane = tid & 63;
  const int quad = lane >> 4, l16 = lane & 15;
  const int wm = wave & 1, wn = wave >> 1;

  const int gx = gridDim.x, gy = gridDim.y, gz = gridDim.z;
  int bx = blockIdx.x, by = blockIdx.y, bz = blockIdx.z;
  if ((gy & 7) == 0) {
    const int i = blockIdx.x + gx * (blockIdx.y + gy * blockIdx.z);
    const int g = i & 7, s = i >> 3;
    const int yg = gy >> 3;
    by = g * yg + (s % yg);
    const int rem = s / yg;
    bx = rem % gx;
    bz = rem / gx;
  }
  const int m0 = by * BM, n0 = bx * 128;
  const int kz = bz;
  const int Kh = K / gz;
  const int kof = kz * Kh;

  __shared__ __align__(16) unsigned short smem[2 * BM * 32 + 2 * 128 * 32];
  unsigned short* As = smem;               // [2][BM*32]
  unsigned short* Bs = smem + 2 * BM * 32; // [2][128*32]

  const int r0 = tid >> 2;
  const int kc = (tid & 3) * 8;
  const unsigned short* Ag[ACP];
#pragma unroll
  for (int i = 0; i < ACP; i++)
    Ag[i] = A + (size_t)(m0 + r0 + 64 * i) * K + kof + kc;
  const unsigned short* Bg[2];
#pragma unroll
  for (int i = 0; i < 2; i++)
    Bg[i] = W + (size_t)(n0 + r0 + 64 * i) * K + kof + kc;

  f32x4 acc[MI][4];
#pragma unroll
  for (int i = 0; i < MI; i++)
#pragma unroll
    for (int j = 0; j < 4; j++) acc[i][j] = (f32x4){0.f, 0.f, 0.f, 0.f};

  auto stage = [&](int koff, int bsel) {
#pragma unroll
    for (int i = 0; i < ACP; i++)
      async_copy16(Ag[i] + koff, &As[bsel * (BM * 32) + (i * 256 + wave * 64) * 8]);
#pragma unroll
    for (int i = 0; i < 2; i++)
      async_copy16(Bg[i] + koff, &Bs[bsel * (128 * 32) + (i * 256 + wave * 64) * 8]);
  };

  stage(0, 0);
  int buf = 0;
  for (int k0 = 0; k0 < Kh; k0 += 32) {
    __syncthreads();
    if (k0 + 32 < Kh) stage(k0 + 32, buf ^ 1);
    bf16x8 af[MI], bfr[4];
#pragma unroll
    for (int i = 0; i < MI; i++)
      af[i] = *(const bf16x8*)&As[buf * (BM * 32) +
                                  (wm * (MI * 16) + i * 16 + l16) * 32 + quad * 8];
#pragma unroll
    for (int j = 0; j < 4; j++)
      bfr[j] = *(const bf16x8*)&Bs[buf * (128 * 32) +
                                   (wn * 64 + j * 16 + l16) * 32 + quad * 8];
#pragma unroll
    for (int i = 0; i < MI; i++)
#pragma unroll
      for (int j = 0; j < 4; j++)
        acc[i][j] =
            __builtin_amdgcn_mfma_f32_16x16x32_bf16(af[i], bfr[j], acc[i][j], 0, 0, 0);
    buf ^= 1;
  }

  if constexpr (OUT_BF16) {
    // ---- coalesced bf16 epilogue (BM=128): LDS stage + uint4 stores ----
    __syncthreads();  // all MFMA LDS reads done; smem reusable
    unsigned short* Ct = smem;  // 64 rows x 140 elems = 8960 <= 16384
#pragma unroll
    for (int h = 0; h < 2; h++) {
      if (wm == h) {
#pragma unroll
        for (int j = 0; j < 4; j++) {
          const float bj = BIAS ? bias[n0 + wn * 64 + j * 16 + l16] : 0.f;
#pragma unroll
          for (int i = 0; i < MI; i++)
#pragma unroll
            for (int r = 0; r < 4; r++) {
              float v = acc[i][j][r] + bj;
              if (RELU) v = v > 0.f ? v : 0.f;
              Ct[(i * 16 + quad * 4 + r) * 140 + wn * 64 + j * 16 + l16] =
                  f2bf(v);
            }
        }
      }
      __syncthreads();
#pragma unroll
      for (int i2 = 0; i2 < 4; i2++) {
        const int flat = i2 * 256 + tid;  // 1024 uint4 = 64 rows x 16
        const int row = flat >> 4, cx = flat & 15;
        *(uint4*)&outb[(size_t)(m0 + h * 64 + row) * N + n0 + cx * 8] =
            *(const uint4*)&Ct[row * 140 + cx * 8];
      }
      __syncthreads();
    }
  } else {
    float* outp = (outf2 != nullptr && kz == gz - 1) ? outf2
                                                     : outf + (size_t)kz * M * N;
#pragma unroll
    for (int j = 0; j < 4; j++) {
      const int col = n0 + wn * 64 + j * 16 + l16;
      const float bj = BIAS ? bias[col] : 0.f;
#pragma unroll
      for (int i = 0; i < MI; i++) {
        const int rowb = m0 + wm * (MI * 16) + i * 16 + quad * 4;
#pragma unroll
        for (int r = 0; r < 4; r++) {
          float v = acc[i][j][r] + bj;
          if (RELU) v = v > 0.f ? v : 0.f;
          outp[(size_t)(rowb + r) * N + col] = v;
        }
      }
    }
  }
}

// ---------------------------------------------------------------------------
// MFMA flash attention, causal (r4-proven version, EXACT: single-buffered
// K/V, in-kernel scalar V transpose, 27.6 KB LDS -> 4 blocks/CU, T5
// setprio + T13 defer-max). Run-to-run noise on this kernel is ~±4 us.
// ---------------------------------------------------------------------------
__global__ __launch_bounds__(256, 4) void attn_mfma(
    const unsigned short* __restrict__ qkv, unsigned short* __restrict__ out) {
  const int tid = threadIdx.x;
  const int w = tid >> 6, lane = tid & 63;
  const int quad = lane >> 4, l16 = lane & 15;
  const int bh = blockIdx.x;
  const int b = bh >> 4, h = bh & 15;
  const int y = blockIdx.y;
  const int t = (y < 8) ? (31 - y) : (y < 16) ? (y - 8) : (y < 24) ? (39 - y)
                                                                   : (y - 16);
  const int qwb = t * 64 + w * 16;  // wave's first q row

  __shared__ __align__(16) unsigned short Ks[64 * 72];     // [k][d]
  __shared__ __align__(16) unsigned short Vt[64 * 72];     // [d][k-swizzled]
  __shared__ __align__(16) unsigned short Pw[4][16 * 72];  // per-wave P [q][k]

  // Q B-frags (x0.125 folded, exact)
  bf16x8 qb[2];
#pragma unroll
  for (int kd = 0; kd < 2; kd++) {
    const unsigned short* qp =
        qkv + (size_t)(b * NL + qwb + l16) * (3 * ND) + h * NDH + kd * 32 + quad * 8;
    union { uint4 u; unsigned short s[8]; bf16x8 v; } qu;
    qu.u = *(const uint4*)qp;
#pragma unroll
    for (int e = 0; e < 8; e++) qu.s[e] = f2bf(bf2f(qu.s[e]) * 0.125f);
    qb[kd] = qu.v;
  }

  float m_s = -INFINITY, l_s = 0.f;
  f32x4 of_[4];
#pragma unroll
  for (int nd = 0; nd < 4; nd++) of_[nd] = (f32x4){0.f, 0.f, 0.f, 0.f};

  const int nch = t + 1;
  for (int c = 0; c < nch; c++) {
    const int kbase = c * 64;
    __syncthreads();
#pragma unroll
    for (int p = 0; p < 2; p++) {
      const int kk = p * 32 + (tid >> 3);
      const int d0 = (tid & 7) * 8;
      const unsigned short* gk =
          qkv + (size_t)(b * NL + kbase + kk) * (3 * ND) + ND + h * NDH + d0;
      uint4 ku = *(const uint4*)gk;
      uint4 vu = *(const uint4*)(gk + ND);
      *(uint4*)&Ks[kk * 72 + d0] = ku;
      const unsigned short* pv = (const unsigned short*)&vu;
      const int kg = kk >> 3, kr = kk & 7;
#pragma unroll
      for (int e = 0; e < 8; e++) {
        const int d = d0 + e;
        Vt[d * 72 + ((kg ^ (d >> 3)) & 7) * 8 + kr] = pv[e];
      }
    }
    __syncthreads();

    f32x4 st[4];
#pragma unroll
    for (int kt = 0; kt < 4; kt++) st[kt] = (f32x4){0.f, 0.f, 0.f, 0.f};
    __builtin_amdgcn_s_setprio(1);
#pragma unroll
    for (int kd = 0; kd < 2; kd++)
#pragma unroll
      for (int kt = 0; kt < 4; kt++) {
        const bf16x8 kaf =
            *(const bf16x8*)&Ks[(kt * 16 + l16) * 72 + kd * 32 + quad * 8];
        st[kt] = __builtin_amdgcn_mfma_f32_16x16x32_bf16(kaf, qb[kd], st[kt], 0, 0, 0);
      }
    __builtin_amdgcn_s_setprio(0);

    if (kbase + 63 > qwb) {
      const int qg_ = qwb + l16;
#pragma unroll
      for (int kt = 0; kt < 4; kt++) {
        const int kg_ = kbase + kt * 16 + quad * 4;
#pragma unroll
        for (int r = 0; r < 4; r++)
          if (kg_ + r > qg_) st[kt][r] = -INFINITY;
      }
    }

    float mx = -INFINITY;
#pragma unroll
    for (int kt = 0; kt < 4; kt++)
#pragma unroll
      for (int r = 0; r < 4; r++) mx = fmaxf(mx, st[kt][r]);
    mx = fmaxf(mx, __shfl_xor(mx, 16, 64));
    mx = fmaxf(mx, __shfl_xor(mx, 32, 64));
    if (!__all(mx <= m_s + 8.f)) {
      const float mnew = fmaxf(m_s, mx);
      const float al = __expf(m_s - mnew);
      m_s = mnew;
      l_s *= al;
#pragma unroll
      for (int r = 0; r < 4; r++) {
        const float ar = __shfl(al, quad * 4 + r, 16);
#pragma unroll
        for (int nd = 0; nd < 4; nd++) of_[nd][r] *= ar;
      }
    }
    float sum = 0.f;
#pragma unroll
    for (int kt = 0; kt < 4; kt++) {
      ushort4 pk_;
#pragma unroll
      for (int r = 0; r < 4; r++) {
        const float pv_ = __expf(st[kt][r] - m_s);
        sum += pv_;
        ((unsigned short*)&pk_)[r] = f2bf(pv_);
      }
      *(ushort4*)&Pw[w][l16 * 72 + kt * 16 + quad * 4] = pk_;
    }
    sum += __shfl_xor(sum, 16, 64);
    sum += __shfl_xor(sum, 32, 64);
    l_s += sum;

    __builtin_amdgcn_s_setprio(1);
#pragma unroll
    for (int kk = 0; kk < 2; kk++) {
      const bf16x8 pa = *(const bf16x8*)&Pw[w][l16 * 72 + kk * 32 + quad * 8];
#pragma unroll
      for (int nd = 0; nd < 4; nd++) {
        const int d = nd * 16 + l16;
        const bf16x8 vbf =
            *(const bf16x8*)&Vt[d * 72 + (((kk * 4 + quad) ^ (d >> 3)) & 7) * 8];
        of_[nd] = __builtin_amdgcn_mfma_f32_16x16x32_bf16(pa, vbf, of_[nd], 0, 0, 0);
      }
    }
    __builtin_amdgcn_s_setprio(0);
  }

  const float li = 1.f / l_s;
#pragma unroll
  for (int r = 0; r < 4; r++) {
    const float lr = __shfl(li, quad * 4 + r, 16);
    const size_t rowoff = (size_t)(b * NL + qwb + quad * 4 + r) * ND + h * NDH;
#pragma unroll
    for (int nd = 0; nd < 4; nd++)
      out[rowoff + nd * 16 + l16] = f2bf(of_[nd][r] * lr);
  }
}

// ---------------------------------------------------------------------------
// (sum of NP partials + bias + res) -> LayerNorm (ddof=1). All f32.
// No __restrict__: p3 may alias of (d_out), block-local read-before-write.
// ---------------------------------------------------------------------------
__device__ __forceinline__ float block_sum256(float v, float* sbuf) {
#pragma unroll
  for (int off = 32; off > 0; off >>= 1) v += __shfl_down(v, off, 64);
  const int tid = threadIdx.x;
  if ((tid & 63) == 0) sbuf[tid >> 6] = v;
  __syncthreads();
  return sbuf[0] + sbuf[1] + sbuf[2] + sbuf[3];
}

template <bool WRITE_BF16, int NP>
__global__ __launch_bounds__(256, 4) void add_ln_kernel(
    const float* p0, const float* p1, const float* p2, const float* p3,
    const float* bias, const float* res, const float* gam, const float* bet,
    float* of, unsigned short* ob) {
  const int row = blockIdx.x, tid = threadIdx.x;
  __shared__ float sbuf[4];
  const size_t base = (size_t)row * ND;
  float x[4];
#pragma unroll
  for (int e = 0; e < 4; e++) {
    const int idx = tid + 256 * e;
    float v = p0[base + idx] + bias[idx] + res[base + idx];
    if (NP >= 2) v += p1[base + idx];
    if (NP > 2) v += p2[base + idx] + p3[base + idx];
    x[e] = v;
  }
  float s = x[0] + x[1] + x[2] + x[3];
  s = block_sum256(s, sbuf);
  const float mean = s * (1.f / (float)ND);
  float sq = 0.f;
#pragma unroll
  for (int e = 0; e < 4; e++) {
    const float d = x[e] - mean;
    sq += d * d;
  }
  __syncthreads();
  sq = block_sum256(sq, sbuf);
  const float inv = 1.f / (sqrtf(sq * (1.f / (float)(ND - 1))) + 1e-6f);
#pragma unroll
  for (int e = 0; e < 4; e++) {
    const int idx = tid + 256 * e;
    const float y = (x[e] - mean) * inv * gam[idx] + bet[idx];
    of[base + idx] = y;
    if (WRITE_BF16) ob[base + idx] = f2bf(y);
  }
}

// ---------------------------------------------------------------------------
extern "C" void kernel_launch(void* const* d_in, const int* in_sizes, int n_in,
                              void* d_out, int out_size, void* d_ws, size_t ws_size,
                              hipStream_t stream) {
  const float* x = (const float*)d_in[0];
  // d_in[1] = mask (int32) — exactly causal, handled analytically
  const float* Wqkv = (const float*)d_in[2];
  const float* bqkv = (const float*)d_in[3];
  const float* Wo = (const float*)d_in[4];
  const float* bo = (const float*)d_in[5];
  const float* ln1a = (const float*)d_in[6];
  const float* ln1b = (const float*)d_in[7];
  const float* W1 = (const float*)d_in[8];
  const float* b1 = (const float*)d_in[9];
  const float* W2 = (const float*)d_in[10];
  const float* b2 = (const float*)d_in[11];
  const float* ln2a = (const float*)d_in[12];
  const float* ln2b = (const float*)d_in[13];

  // workspace layout (MiB); peak 112 (r4-proven layout, unchanged)
  char* ws = (char*)d_ws;
  unsigned short* qkv = (unsigned short*)(ws);
  unsigned short* ffn1 = (unsigned short*)(ws);
  unsigned short* Wqkvb = (unsigned short*)(ws + 25165824);
  unsigned short* aout = (unsigned short*)(ws + 25165824);
  unsigned short* xb = (unsigned short*)(ws + 33554432);
  float* pWo = (float*)(ws + 33554432);
  float* pW2 = (float*)(ws + 33554432);
  unsigned short* Wob = (unsigned short*)(ws + 67108864);
  unsigned short* W1b = (unsigned short*)(ws + 69206016);
  float* hf = (float*)(ws + 83886080);
  unsigned short* hb = (unsigned short*)(ws + 100663296);
  unsigned short* W2b = (unsigned short*)(ws + 109051904);

  const int M = NB * NL;  // 4096
  const size_t MN = (size_t)M * ND;
  dim3 blk(256);

  // 0) all f32->bf16 casts in one launch
  cast_all<<<dim3(16384), blk, 0, stream>>>(x, Wqkv, Wo, W1, W2, xb, Wqkvb, Wob,
                                            W1b, W2b);
  // 1) qkv = x @ Wqkv^T + bqkv -> bf16 (128^2, 768 blocks; coalesced epi)
  gemm_bt<128, false, true, true><<<dim3(3 * ND / 128, M / 128), blk, 0, stream>>>(
      xb, Wqkvb, bqkv, qkv, nullptr, nullptr, M, 3 * ND, ND);
  // 2) attention -> aout bf16 (64-row q-tiles, 1024 blocks, long-first order)
  attn_mfma<<<dim3(NB * NH, NL / 64), blk, 0, stream>>>(qkv, aout);
  // 3) Wo partials (BM=64, split-K x2 -> 1024 blocks): pWo + z*M*N
  gemm_bt<64, false, false, false><<<dim3(ND / 128, M / 64, 2), blk, 0, stream>>>(
      aout, Wob, nullptr, nullptr, pWo, nullptr, M, ND, ND);
  // 4) h = LN(x + p0 + p1 + bo) -> hf (f32) + hb (bf16)
  add_ln_kernel<true, 2><<<dim3(M), blk, 0, stream>>>(
      pWo, pWo + MN, pWo, pWo, bo, x, ln1a, ln1b, hf, hb);
  // 5) ffn1 = relu(h @ W1^T + b1) -> bf16 (256^2, 256 blocks; coalesced epi)
  gemm256<true><<<dim3(NDFF / 256, M / 256), dim3(512), 0, stream>>>(
      hb, W1b, b1, ffn1, M, NDFF, ND);
  // 6) W2 partials (BM=128, split-K x4 -> 1024 blocks):
  //    slots 0-2 in pW2, slot 3 in d_out
  gemm_bt<128, false, false, false><<<dim3(ND / 128, M / 128, 4), blk, 0, stream>>>(
      ffn1, W2b, nullptr, nullptr, pW2, (float*)d_out, M, ND, NDFF);
  // 7) out = LN(hf + p0+p1+p2+p3 + b2) -> f32 d_out (p3 aliases d_out: safe)
  add_ln_kernel<false, 4><<<dim3(M), blk, 0, stream>>>(
      pW2, pW2 + MN, pW2 + 2 * MN, (float*)d_out, b2, hf, ln2a, ln2b,
      (float*)d_out, nullptr);
}

// Round 15
// 350.585 us; speedup vs baseline: 1.0373x; 1.0184x over previous
//
#include <hip/hip_runtime.h>
#include <cstdint>
#include <cstddef>

#define NB 2
#define NL 2048
#define ND 1024
#define NH 16
#define NDH 64
#define NDFF 4096

typedef __bf16 bf16_t;
typedef bf16_t bf16x8 __attribute__((ext_vector_type(8)));
typedef float f32x4 __attribute__((ext_vector_type(4)));

__device__ __forceinline__ float bf2f(unsigned short h) {
  union { unsigned u; float f; } c; c.u = ((unsigned)h) << 16; return c.f;
}
__device__ __forceinline__ unsigned short f2bf(float f) {
  union { float f; unsigned u; } c; c.f = f;
  return (unsigned short)((c.u + 0x7fffu + ((c.u >> 16) & 1u)) >> 16);
}

// async global->LDS, 16B per lane; lds base must be wave-uniform.
__device__ __forceinline__ void async_copy16(const void* g, void* l) {
  __builtin_amdgcn_global_load_lds(
      (const __attribute__((address_space(1))) void*)g,
      (__attribute__((address_space(3))) void*)l, 16, 0, 0);
}

// ---------------------------------------------------------------------------
// Fused f32 -> bf16 cast of x + all 4 weight matrices, one launch.
// ---------------------------------------------------------------------------
__global__ __launch_bounds__(256) void cast_all(
    const float* __restrict__ x, const float* __restrict__ wqkv,
    const float* __restrict__ wo, const float* __restrict__ w1,
    const float* __restrict__ w2, unsigned short* __restrict__ xb,
    unsigned short* __restrict__ wqkvb, unsigned short* __restrict__ wob,
    unsigned short* __restrict__ w1b, unsigned short* __restrict__ w2b) {
  const int i = blockIdx.x * 256 + threadIdx.x;
  const float* src;
  unsigned short* dst;
  int off;
  if (i < 1048576) { src = x; dst = xb; off = i; }  // 4M elems (vec4)
  else if (i < 1835008) { src = wqkv; dst = wqkvb; off = i - 1048576; }
  else if (i < 2097152) { src = wo; dst = wob; off = i - 1835008; }
  else if (i < 3145728) { src = w1; dst = w1b; off = i - 2097152; }
  else { src = w2; dst = w2b; off = i - 3145728; }
  const float4 v = ((const float4*)src)[off];
  ushort4 o;
  o.x = f2bf(v.x); o.y = f2bf(v.y); o.z = f2bf(v.z); o.w = f2bf(v.w);
  ((ushort4*)dst)[off] = o;
}

// ---------------------------------------------------------------------------
// 256x256 8-wave GEMM, BK=64 (ffn1 only: 256 blocks = 1/CU perfect fill).
// r13 PROVEN: LDS-staged coalesced epilogue cut WRITE 81.6->~33 MB and
// dur 69.4 -> <54 us. Main loop: stage-next + counted vmcnt(8) + raw
// s_barrier + 4 phases x {ds_read, setprio, 16 MFMA}; granule swizzle
// both-sides (bank conflicts measured 0).
// ---------------------------------------------------------------------------
template <bool RELU>
__global__ __launch_bounds__(512, 2) void gemm256(
    const unsigned short* __restrict__ A, const unsigned short* __restrict__ W,
    const float* __restrict__ bias, unsigned short* __restrict__ outb,
    int M, int N, int K) {
  const int tid = threadIdx.x;
  const int lane = tid & 63;
  const int wid = tid >> 6;
  const int wm = wid >> 2, wn = wid & 3;
  const int quad = lane >> 4, l16 = lane & 15;

  // XCD-aware remap (gy multiple of 8)
  const int gx = gridDim.x, gy = gridDim.y;
  int bx = blockIdx.x, by = blockIdx.y;
  if ((gy & 7) == 0) {
    const int i = blockIdx.x + gx * blockIdx.y;
    const int g = i & 7, s = i >> 3;
    const int yg = gy >> 3;
    by = g * yg + (s % yg);
    bx = (s / yg) % gx;
  }
  const int m0 = by * 256, n0 = bx * 256;

  __shared__ __align__(16) unsigned short smem[65536];  // 128 KiB
  unsigned short* As = smem;          // [2][256*64]
  unsigned short* Bs = smem + 32768;  // [2][256*64]

  // staging: load l covers row l*64 + (tid>>3); source granule pre-swizzled
  const int srow = tid >> 3;                 // 0..63
  const int gsrc = (tid & 7) ^ (srow & 7);   // logical granule for this slot
  const unsigned short* Ag = A + (size_t)(m0 + srow) * K + gsrc * 8;
  const unsigned short* Bg = W + (size_t)(n0 + srow) * K + gsrc * 8;
  const int ldst = srow * 64 + (tid & 7) * 8;  // linear LDS elem offset

  f32x4 acc[8][4];
#pragma unroll
  for (int i = 0; i < 8; i++)
#pragma unroll
    for (int j = 0; j < 4; j++) acc[i][j] = (f32x4){0.f, 0.f, 0.f, 0.f};

  auto stage = [&](int kt, int bsel) {
#pragma unroll
    for (int l = 0; l < 4; l++)
      async_copy16(Ag + (size_t)(l * 64) * K + kt * 64,
                   &As[bsel * 16384 + l * 64 * 64 + ldst]);
#pragma unroll
    for (int l = 0; l < 4; l++)
      async_copy16(Bg + (size_t)(l * 64) * K + kt * 64,
                   &Bs[bsel * 16384 + l * 64 * 64 + ldst]);
  };

  // read-side addressing: row&7 == l16&7 for both A and B fragments
  const int arow = wm * 128 + l16;  // + mf*16
  const int brow = wn * 64 + l16;   // + nf*16
  const int r7 = l16 & 7;

  const int NT = K >> 6;
  int b = 0;
  stage(0, 0);
  for (int kt = 0; kt < NT; kt++) {
    if (kt + 1 < NT) {
      stage(kt + 1, b ^ 1);  // 8 more loads in flight
      asm volatile("s_waitcnt vmcnt(8)" ::: "memory");  // this tile's done
    } else {
      asm volatile("s_waitcnt vmcnt(0)" ::: "memory");
    }
    __builtin_amdgcn_s_barrier();  // all waves' staging visible

#pragma unroll
    for (int ph = 0; ph < 4; ph++) {
      const int mh = ph >> 1, nh = ph & 1;
      bf16x8 a_[4][2], b_[2][2];
#pragma unroll
      for (int mf = 0; mf < 4; mf++)
#pragma unroll
        for (int kk = 0; kk < 2; kk++)
          a_[mf][kk] = *(const bf16x8*)&As[b * 16384 +
                                          (arow + (mh * 4 + mf) * 16) * 64 +
                                          (((quad + kk * 4) ^ r7) * 8)];
#pragma unroll
      for (int nf = 0; nf < 2; nf++)
#pragma unroll
        for (int kk = 0; kk < 2; kk++)
          b_[nf][kk] = *(const bf16x8*)&Bs[b * 16384 +
                                          (brow + (nh * 2 + nf) * 16) * 64 +
                                          (((quad + kk * 4) ^ r7) * 8)];
      __builtin_amdgcn_s_setprio(1);
#pragma unroll
      for (int mf = 0; mf < 4; mf++)
#pragma unroll
        for (int nf = 0; nf < 2; nf++)
#pragma unroll
          for (int kk = 0; kk < 2; kk++)
            acc[mh * 4 + mf][nh * 2 + nf] = __builtin_amdgcn_mfma_f32_16x16x32_bf16(
                a_[mf][kk], b_[nf][kk], acc[mh * 4 + mf][nh * 2 + nf], 0, 0, 0);
      __builtin_amdgcn_s_setprio(0);
    }
    __builtin_amdgcn_s_barrier();  // reads of buf b done; safe to restage
    b ^= 1;
  }

  // ---- coalesced epilogue: acc -> LDS (padded) -> uint4 global stores ----
  __syncthreads();  // all MFMA LDS reads done; smem reusable
  unsigned short* Ct = smem;  // 128 rows x 268 elems = 34304 <= 65536
#pragma unroll
  for (int h = 0; h < 2; h++) {
    if (wm == h) {
#pragma unroll
      for (int nf = 0; nf < 4; nf++) {
        const float bj = bias[n0 + wn * 64 + nf * 16 + l16];
#pragma unroll
        for (int mf = 0; mf < 8; mf++)
#pragma unroll
          for (int r = 0; r < 4; r++) {
            float v = acc[mf][nf][r] + bj;
            if (RELU) v = v > 0.f ? v : 0.f;
            Ct[(mf * 16 + quad * 4 + r) * 268 + wn * 64 + nf * 16 + l16] =
                f2bf(v);
          }
      }
    }
    __syncthreads();
#pragma unroll
    for (int i2 = 0; i2 < 8; i2++) {
      const int flat = i2 * 512 + tid;  // 4096 uint4 = 128 rows x 32
      const int row = flat >> 5, cx = flat & 31;
      *(uint4*)&outb[(size_t)(m0 + h * 128 + row) * N + n0 + cx * 8] =
          *(const uint4*)&Ct[row * 268 + cx * 8];
    }
    __syncthreads();
  }
}

// ---------------------------------------------------------------------------
// GEMM: C[M,N] = A[M,K] @ W[N,K]^T (+ bias[N]) (A,W bf16; C bf16/f32)
// BMx128 tile, BK=32, 4 waves 2x2 (r4-proven main loop). r14: bf16
// epilogue = DIRECT stores, column-loop INNERMOST. r13's LDS-staged
// variant regressed (+13 us on qkv): serial tail latency at 3 blocks/CU
// costs more than the traffic it saves. Mechanism insight (attn writes
// the same 16-lane x 2B pattern with ZERO amplification because its
// column loop is innermost): 4 consecutive 32B stores covering one 128B
// line merge in the write buffer; j-outermost scattered them ~128 insts
// apart -> 2.55x amplification (r11 measured). Reordering = free fix.
// f32 partial path (64B segments, no amplification) unchanged.
// ---------------------------------------------------------------------------
template <int BM, bool RELU, bool OUT_BF16, bool BIAS>
__global__ __launch_bounds__(256, 3) void gemm_bt(
    const unsigned short* __restrict__ A, const unsigned short* __restrict__ W,
    const float* __restrict__ bias, unsigned short* __restrict__ outb,
    float* __restrict__ outf, float* __restrict__ outf2, int M, int N, int K) {
  constexpr int MI = BM / 32;   // mfma m-tiles per wave (4 or 2)
  constexpr int ACP = BM / 64;  // A staging copies (2 or 1)
  const int tid = threadIdx.x;
  const int wave = tid >> 6, lane = tid & 63;
  const int quad = lane >> 4, l16 = lane & 15;
  const int wm = wave & 1, wn = wave >> 1;

  const int gx = gridDim.x, gy = gridDim.y, gz = gridDim.z;
  int bx = blockIdx.x, by = blockIdx.y, bz = blockIdx.z;
  if ((gy & 7) == 0) {
    const int i = blockIdx.x + gx * (blockIdx.y + gy * blockIdx.z);
    const int g = i & 7, s = i >> 3;
    const int yg = gy >> 3;
    by = g * yg + (s % yg);
    const int rem = s / yg;
    bx = rem % gx;
    bz = rem / gx;
  }
  const int m0 = by * BM, n0 = bx * 128;
  const int kz = bz;
  const int Kh = K / gz;
  const int kof = kz * Kh;

  __shared__ __align__(16) unsigned short As[2][BM * 32];
  __shared__ __align__(16) unsigned short Bs[2][128 * 32];

  const int r0 = tid >> 2;
  const int kc = (tid & 3) * 8;
  const unsigned short* Ag[ACP];
#pragma unroll
  for (int i = 0; i < ACP; i++)
    Ag[i] = A + (size_t)(m0 + r0 + 64 * i) * K + kof + kc;
  const unsigned short* Bg[2];
#pragma unroll
  for (int i = 0; i < 2; i++)
    Bg[i] = W + (size_t)(n0 + r0 + 64 * i) * K + kof + kc;

  f32x4 acc[MI][4];
#pragma unroll
  for (int i = 0; i < MI; i++)
#pragma unroll
    for (int j = 0; j < 4; j++) acc[i][j] = (f32x4){0.f, 0.f, 0.f, 0.f};

  auto stage = [&](int koff, int bsel) {
#pragma unroll
    for (int i = 0; i < ACP; i++)
      async_copy16(Ag[i] + koff, &As[bsel][(i * 256 + wave * 64) * 8]);
#pragma unroll
    for (int i = 0; i < 2; i++)
      async_copy16(Bg[i] + koff, &Bs[bsel][(i * 256 + wave * 64) * 8]);
  };

  stage(0, 0);
  int buf = 0;
  for (int k0 = 0; k0 < Kh; k0 += 32) {
    __syncthreads();
    if (k0 + 32 < Kh) stage(k0 + 32, buf ^ 1);
    bf16x8 af[MI], bfr[4];
#pragma unroll
    for (int i = 0; i < MI; i++)
      af[i] =
          *(const bf16x8*)&As[buf][(wm * (MI * 16) + i * 16 + l16) * 32 + quad * 8];
#pragma unroll
    for (int j = 0; j < 4; j++)
      bfr[j] = *(const bf16x8*)&Bs[buf][(wn * 64 + j * 16 + l16) * 32 + quad * 8];
#pragma unroll
    for (int i = 0; i < MI; i++)
#pragma unroll
      for (int j = 0; j < 4; j++)
        acc[i][j] =
            __builtin_amdgcn_mfma_f32_16x16x32_bf16(af[i], bfr[j], acc[i][j], 0, 0, 0);
    buf ^= 1;
  }

  if constexpr (OUT_BF16) {
    // direct bf16 stores, column (j) INNERMOST: 4 consecutive 32B stores
    // per row cover one full 128B line -> write-buffer merge, no
    // amplification (attn-verified pattern), no LDS round-trip.
#pragma unroll
    for (int i = 0; i < MI; i++) {
#pragma unroll
      for (int r = 0; r < 4; r++) {
        const size_t rowoff = (size_t)(m0 + wm * (MI * 16) + i * 16 + quad * 4 + r) * N;
#pragma unroll
        for (int j = 0; j < 4; j++) {
          const int col = n0 + wn * 64 + j * 16 + l16;
          float v = acc[i][j][r] + (BIAS ? bias[col] : 0.f);
          if (RELU) v = v > 0.f ? v : 0.f;
          outb[rowoff + col] = f2bf(v);
        }
      }
    }
  } else {
    float* outp = (outf2 != nullptr && kz == gz - 1) ? outf2
                                                     : outf + (size_t)kz * M * N;
#pragma unroll
    for (int j = 0; j < 4; j++) {
      const int col = n0 + wn * 64 + j * 16 + l16;
      const float bj = BIAS ? bias[col] : 0.f;
#pragma unroll
      for (int i = 0; i < MI; i++) {
        const int rowb = m0 + wm * (MI * 16) + i * 16 + quad * 4;
#pragma unroll
        for (int r = 0; r < 4; r++) {
          float v = acc[i][j][r] + bj;
          if (RELU) v = v > 0.f ? v : 0.f;
          outp[(size_t)(rowb + r) * N + col] = v;
        }
      }
    }
  }
}

// ---------------------------------------------------------------------------
// MFMA flash attention, causal (r4-proven version, EXACT: single-buffered
// K/V, in-kernel scalar V transpose, 27.6 KB LDS -> 4 blocks/CU, T5
// setprio + T13 defer-max). Run-to-run noise on this kernel is ~±4 us.
// ---------------------------------------------------------------------------
__global__ __launch_bounds__(256, 4) void attn_mfma(
    const unsigned short* __restrict__ qkv, unsigned short* __restrict__ out) {
  const int tid = threadIdx.x;
  const int w = tid >> 6, lane = tid & 63;
  const int quad = lane >> 4, l16 = lane & 15;
  const int bh = blockIdx.x;
  const int b = bh >> 4, h = bh & 15;
  const int y = blockIdx.y;
  const int t = (y < 8) ? (31 - y) : (y < 16) ? (y - 8) : (y < 24) ? (39 - y)
                                                                   : (y - 16);
  const int qwb = t * 64 + w * 16;  // wave's first q row

  __shared__ __align__(16) unsigned short Ks[64 * 72];     // [k][d]
  __shared__ __align__(16) unsigned short Vt[64 * 72];     // [d][k-swizzled]
  __shared__ __align__(16) unsigned short Pw[4][16 * 72];  // per-wave P [q][k]

  // Q B-frags (x0.125 folded, exact)
  bf16x8 qb[2];
#pragma unroll
  for (int kd = 0; kd < 2; kd++) {
    const unsigned short* qp =
        qkv + (size_t)(b * NL + qwb + l16) * (3 * ND) + h * NDH + kd * 32 + quad * 8;
    union { uint4 u; unsigned short s[8]; bf16x8 v; } qu;
    qu.u = *(const uint4*)qp;
#pragma unroll
    for (int e = 0; e < 8; e++) qu.s[e] = f2bf(bf2f(qu.s[e]) * 0.125f);
    qb[kd] = qu.v;
  }

  float m_s = -INFINITY, l_s = 0.f;
  f32x4 of_[4];
#pragma unroll
  for (int nd = 0; nd < 4; nd++) of_[nd] = (f32x4){0.f, 0.f, 0.f, 0.f};

  const int nch = t + 1;
  for (int c = 0; c < nch; c++) {
    const int kbase = c * 64;
    __syncthreads();
#pragma unroll
    for (int p = 0; p < 2; p++) {
      const int kk = p * 32 + (tid >> 3);
      const int d0 = (tid & 7) * 8;
      const unsigned short* gk =
          qkv + (size_t)(b * NL + kbase + kk) * (3 * ND) + ND + h * NDH + d0;
      uint4 ku = *(const uint4*)gk;
      uint4 vu = *(const uint4*)(gk + ND);
      *(uint4*)&Ks[kk * 72 + d0] = ku;
      const unsigned short* pv = (const unsigned short*)&vu;
      const int kg = kk >> 3, kr = kk & 7;
#pragma unroll
      for (int e = 0; e < 8; e++) {
        const int d = d0 + e;
        Vt[d * 72 + ((kg ^ (d >> 3)) & 7) * 8 + kr] = pv[e];
      }
    }
    __syncthreads();

    f32x4 st[4];
#pragma unroll
    for (int kt = 0; kt < 4; kt++) st[kt] = (f32x4){0.f, 0.f, 0.f, 0.f};
    __builtin_amdgcn_s_setprio(1);
#pragma unroll
    for (int kd = 0; kd < 2; kd++)
#pragma unroll
      for (int kt = 0; kt < 4; kt++) {
        const bf16x8 kaf =
            *(const bf16x8*)&Ks[(kt * 16 + l16) * 72 + kd * 32 + quad * 8];
        st[kt] = __builtin_amdgcn_mfma_f32_16x16x32_bf16(kaf, qb[kd], st[kt], 0, 0, 0);
      }
    __builtin_amdgcn_s_setprio(0);

    if (kbase + 63 > qwb) {
      const int qg_ = qwb + l16;
#pragma unroll
      for (int kt = 0; kt < 4; kt++) {
        const int kg_ = kbase + kt * 16 + quad * 4;
#pragma unroll
        for (int r = 0; r < 4; r++)
          if (kg_ + r > qg_) st[kt][r] = -INFINITY;
      }
    }

    float mx = -INFINITY;
#pragma unroll
    for (int kt = 0; kt < 4; kt++)
#pragma unroll
      for (int r = 0; r < 4; r++) mx = fmaxf(mx, st[kt][r]);
    mx = fmaxf(mx, __shfl_xor(mx, 16, 64));
    mx = fmaxf(mx, __shfl_xor(mx, 32, 64));
    if (!__all(mx <= m_s + 8.f)) {
      const float mnew = fmaxf(m_s, mx);
      const float al = __expf(m_s - mnew);
      m_s = mnew;
      l_s *= al;
#pragma unroll
      for (int r = 0; r < 4; r++) {
        const float ar = __shfl(al, quad * 4 + r, 16);
#pragma unroll
        for (int nd = 0; nd < 4; nd++) of_[nd][r] *= ar;
      }
    }
    float sum = 0.f;
#pragma unroll
    for (int kt = 0; kt < 4; kt++) {
      ushort4 pk_;
#pragma unroll
      for (int r = 0; r < 4; r++) {
        const float pv_ = __expf(st[kt][r] - m_s);
        sum += pv_;
        ((unsigned short*)&pk_)[r] = f2bf(pv_);
      }
      *(ushort4*)&Pw[w][l16 * 72 + kt * 16 + quad * 4] = pk_;
    }
    sum += __shfl_xor(sum, 16, 64);
    sum += __shfl_xor(sum, 32, 64);
    l_s += sum;

    __builtin_amdgcn_s_setprio(1);
#pragma unroll
    for (int kk = 0; kk < 2; kk++) {
      const bf16x8 pa = *(const bf16x8*)&Pw[w][l16 * 72 + kk * 32 + quad * 8];
#pragma unroll
      for (int nd = 0; nd < 4; nd++) {
        const int d = nd * 16 + l16;
        const bf16x8 vbf =
            *(const bf16x8*)&Vt[d * 72 + (((kk * 4 + quad) ^ (d >> 3)) & 7) * 8];
        of_[nd] = __builtin_amdgcn_mfma_f32_16x16x32_bf16(pa, vbf, of_[nd], 0, 0, 0);
      }
    }
    __builtin_amdgcn_s_setprio(0);
  }

  const float li = 1.f / l_s;
#pragma unroll
  for (int r = 0; r < 4; r++) {
    const float lr = __shfl(li, quad * 4 + r, 16);
    const size_t rowoff = (size_t)(b * NL + qwb + quad * 4 + r) * ND + h * NDH;
#pragma unroll
    for (int nd = 0; nd < 4; nd++)
      out[rowoff + nd * 16 + l16] = f2bf(of_[nd][r] * lr);
  }
}

// ---------------------------------------------------------------------------
// (sum of NP partials + bias + res) -> LayerNorm (ddof=1). All f32.
// No __restrict__: p3 may alias of (d_out), block-local read-before-write.
// ---------------------------------------------------------------------------
__device__ __forceinline__ float block_sum256(float v, float* sbuf) {
#pragma unroll
  for (int off = 32; off > 0; off >>= 1) v += __shfl_down(v, off, 64);
  const int tid = threadIdx.x;
  if ((tid & 63) == 0) sbuf[tid >> 6] = v;
  __syncthreads();
  return sbuf[0] + sbuf[1] + sbuf[2] + sbuf[3];
}

template <bool WRITE_BF16, int NP>
__global__ __launch_bounds__(256, 4) void add_ln_kernel(
    const float* p0, const float* p1, const float* p2, const float* p3,
    const float* bias, const float* res, const float* gam, const float* bet,
    float* of, unsigned short* ob) {
  const int row = blockIdx.x, tid = threadIdx.x;
  __shared__ float sbuf[4];
  const size_t base = (size_t)row * ND;
  float x[4];
#pragma unroll
  for (int e = 0; e < 4; e++) {
    const int idx = tid + 256 * e;
    float v = p0[base + idx] + bias[idx] + res[base + idx];
    if (NP >= 2) v += p1[base + idx];
    if (NP > 2) v += p2[base + idx] + p3[base + idx];
    x[e] = v;
  }
  float s = x[0] + x[1] + x[2] + x[3];
  s = block_sum256(s, sbuf);
  const float mean = s * (1.f / (float)ND);
  float sq = 0.f;
#pragma unroll
  for (int e = 0; e < 4; e++) {
    const float d = x[e] - mean;
    sq += d * d;
  }
  __syncthreads();
  sq = block_sum256(sq, sbuf);
  const float inv = 1.f / (sqrtf(sq * (1.f / (float)(ND - 1))) + 1e-6f);
#pragma unroll
  for (int e = 0; e < 4; e++) {
    const int idx = tid + 256 * e;
    const float y = (x[e] - mean) * inv * gam[idx] + bet[idx];
    of[base + idx] = y;
    if (WRITE_BF16) ob[base + idx] = f2bf(y);
  }
}

// ---------------------------------------------------------------------------
extern "C" void kernel_launch(void* const* d_in, const int* in_sizes, int n_in,
                              void* d_out, int out_size, void* d_ws, size_t ws_size,
                              hipStream_t stream) {
  const float* x = (const float*)d_in[0];
  // d_in[1] = mask (int32) — exactly causal, handled analytically
  const float* Wqkv = (const float*)d_in[2];
  const float* bqkv = (const float*)d_in[3];
  const float* Wo = (const float*)d_in[4];
  const float* bo = (const float*)d_in[5];
  const float* ln1a = (const float*)d_in[6];
  const float* ln1b = (const float*)d_in[7];
  const float* W1 = (const float*)d_in[8];
  const float* b1 = (const float*)d_in[9];
  const float* W2 = (const float*)d_in[10];
  const float* b2 = (const float*)d_in[11];
  const float* ln2a = (const float*)d_in[12];
  const float* ln2b = (const float*)d_in[13];

  // workspace layout (MiB); peak 112 (r4-proven layout, unchanged)
  char* ws = (char*)d_ws;
  unsigned short* qkv = (unsigned short*)(ws);
  unsigned short* ffn1 = (unsigned short*)(ws);
  unsigned short* Wqkvb = (unsigned short*)(ws + 25165824);
  unsigned short* aout = (unsigned short*)(ws + 25165824);
  unsigned short* xb = (unsigned short*)(ws + 33554432);
  float* pWo = (float*)(ws + 33554432);
  float* pW2 = (float*)(ws + 33554432);
  unsigned short* Wob = (unsigned short*)(ws + 67108864);
  unsigned short* W1b = (unsigned short*)(ws + 69206016);
  float* hf = (float*)(ws + 83886080);
  unsigned short* hb = (unsigned short*)(ws + 100663296);
  unsigned short* W2b = (unsigned short*)(ws + 109051904);

  const int M = NB * NL;  // 4096
  const size_t MN = (size_t)M * ND;
  dim3 blk(256);

  // 0) all f32->bf16 casts in one launch
  cast_all<<<dim3(16384), blk, 0, stream>>>(x, Wqkv, Wo, W1, W2, xb, Wqkvb, Wob,
                                            W1b, W2b);
  // 1) qkv = x @ Wqkv^T + bqkv -> bf16 (128^2, 768 blocks; merged-write epi)
  gemm_bt<128, false, true, true><<<dim3(3 * ND / 128, M / 128), blk, 0, stream>>>(
      xb, Wqkvb, bqkv, qkv, nullptr, nullptr, M, 3 * ND, ND);
  // 2) attention -> aout bf16 (64-row q-tiles, 1024 blocks, long-first order)
  attn_mfma<<<dim3(NB * NH, NL / 64), blk, 0, stream>>>(qkv, aout);
  // 3) Wo partials (BM=64, split-K x2 -> 1024 blocks): pWo + z*M*N
  gemm_bt<64, false, false, false><<<dim3(ND / 128, M / 64, 2), blk, 0, stream>>>(
      aout, Wob, nullptr, nullptr, pWo, nullptr, M, ND, ND);
  // 4) h = LN(x + p0 + p1 + bo) -> hf (f32) + hb (bf16)
  add_ln_kernel<true, 2><<<dim3(M), blk, 0, stream>>>(
      pWo, pWo + MN, pWo, pWo, bo, x, ln1a, ln1b, hf, hb);
  // 5) ffn1 = relu(h @ W1^T + b1) -> bf16 (256^2, 256 blocks; LDS epi, proven)
  gemm256<true><<<dim3(NDFF / 256, M / 256), dim3(512), 0, stream>>>(
      hb, W1b, b1, ffn1, M, NDFF, ND);
  // 6) W2 partials (BM=128, split-K x4 -> 1024 blocks):
  //    slots 0-2 in pW2, slot 3 in d_out
  gemm_bt<128, false, false, false><<<dim3(ND / 128, M / 128, 4), blk, 0, stream>>>(
      ffn1, W2b, nullptr, nullptr, pW2, (float*)d_out, M, ND, NDFF);
  // 7) out = LN(hf + p0+p1+p2+p3 + b2) -> f32 d_out (p3 aliases d_out: safe)
  add_ln_kernel<false, 4><<<dim3(M), blk, 0, stream>>>(
      pW2, pW2 + MN, pW2 + 2 * MN, (float*)d_out, b2, hf, ln2a, ln2b,
      (float*)d_out, nullptr);
}